// Round 14
// baseline (163.347 us; speedup 1.0000x reference)
//
#include <hip/hip_runtime.h>

// ---------------------------------------------------------------------------
// Causal MHA block: QKV proj (bf16 MFMA) -> flash attention -> out proj.
// B=2, S=2048, E=1024, H=16, D=64.
// r14: attention = 32x32x16 MFMA structure (layout verified r11) with KV-SPLIT:
// each 128-row q-tile's KV range is split across TWO 4-wave blocks (equal
// lengths, co-resident -> 8 waves/CU sustained); partial (acc,m,l) merged by a
// combine kernel.  Partials live in d_out (16MB, fully overwritten by gemm_o);
// m/l in the dead WqT region.  GEMMs/converts unchanged from r13.
// ---------------------------------------------------------------------------

#define EMB 1024
#define SEQ 2048
#define NB 2
#define NH 16
#define HD 64

// 0.125 (1/sqrt(64)) * log2(e): QK logits land in exp2 domain
#define QSCALE 0.18033688011112042f

typedef float f32x4 __attribute__((ext_vector_type(4)));
typedef float f32x16 __attribute__((ext_vector_type(16)));
typedef float floatx4 __attribute__((ext_vector_type(4)));
typedef short short8 __attribute__((ext_vector_type(8)));
typedef __bf16 bf16x8 __attribute__((ext_vector_type(8)));
typedef __bf16 bf16x2 __attribute__((ext_vector_type(2)));
typedef unsigned short ushortx4 __attribute__((ext_vector_type(4)));
typedef unsigned int uintx4 __attribute__((ext_vector_type(4)));
typedef int int2v __attribute__((ext_vector_type(2)));

__device__ __forceinline__ unsigned short bf16u(float f) {
  __bf16 h = (__bf16)f;
  return __builtin_bit_cast(unsigned short, h);
}

__device__ __forceinline__ float bf2f(unsigned short u) {
  return __builtin_bit_cast(float, ((unsigned)u) << 16);
}

__device__ __forceinline__ unsigned pkbf(float lo, float hi) {
  bf16x2 v;
  v[0] = (__bf16)lo;
  v[1] = (__bf16)hi;
  return __builtin_bit_cast(unsigned, v);
}

__device__ __forceinline__ f32x4 mfma16(short8 a, short8 b, f32x4 c) {
  return __builtin_amdgcn_mfma_f32_16x16x32_bf16(
      __builtin_bit_cast(bf16x8, a), __builtin_bit_cast(bf16x8, b), c, 0, 0, 0);
}

__device__ __forceinline__ f32x16 mfma32(short8 a, short8 b, f32x16 c) {
  return __builtin_amdgcn_mfma_f32_32x32x16_bf16(
      __builtin_bit_cast(bf16x8, a), __builtin_bit_cast(bf16x8, b), c, 0, 0, 0);
}

// v_permlane32_swap_b32: a.hi <-> b.lo (both results returned)
__device__ __forceinline__ void plswap(unsigned& a, unsigned& b) {
  int2v r = __builtin_amdgcn_permlane32_swap((int)a, (int)b, false, false);
  a = (unsigned)r[0];
  b = (unsigned)r[1];
}

// async global -> LDS, 16B per lane; lds dest is wave-uniform base + lane*16
__device__ __forceinline__ void gload16(const void* g, void* lds) {
  __builtin_amdgcn_global_load_lds(
      (const __attribute__((address_space(1))) unsigned int*)g,
      (__attribute__((address_space(3))) unsigned int*)lds, 16, 0, 0);
}

// ---------------------------------------------------------------------------
// Merged converts: z<4 -> fp32 W[k][n] -> bf16 WT[n][k] (32x32 LDS transpose);
// z==4 -> fp32 x -> bf16 (16 elements/thread, float4-coalesced).
// ---------------------------------------------------------------------------
__global__ __launch_bounds__(256) void cvt_all_kernel(
    const float* __restrict__ x, unsigned short* __restrict__ Xb,
    const float* __restrict__ W0, const float* __restrict__ W1,
    const float* __restrict__ W2, const float* __restrict__ W3,
    unsigned short* __restrict__ T0, unsigned short* __restrict__ T1,
    unsigned short* __restrict__ T2, unsigned short* __restrict__ T3) {
  const int z = blockIdx.z;
  const int t = threadIdx.x;
  if (z == 4) {
    const int blin = blockIdx.y * 32 + blockIdx.x;
    const int base = blin * 4096 + t * 4;
    #pragma unroll
    for (int c = 0; c < 4; ++c) {
      const int idx = base + c * 1024;
      floatx4 v = *(const floatx4*)(x + idx);
      ushortx4 o;
      #pragma unroll
      for (int i = 0; i < 4; ++i) o[i] = bf16u(v[i]);
      *(ushortx4*)(Xb + idx) = o;
    }
    return;
  }
  __shared__ unsigned short tile[32][33];
  const float* W = (z == 0) ? W0 : (z == 1) ? W1 : (z == 2) ? W2 : W3;
  unsigned short* WT = (z == 0) ? T0 : (z == 1) ? T1 : (z == 2) ? T2 : T3;
  const int k0 = blockIdx.x * 32, n0 = blockIdx.y * 32;
  const int r = t >> 3, c = (t & 7) * 4;
  floatx4 v = *(const floatx4*)(W + (k0 + r) * EMB + n0 + c);
  #pragma unroll
  for (int i = 0; i < 4; ++i) tile[r][c + i] = bf16u(v[i]);
  __syncthreads();
  ushortx4 o;
  #pragma unroll
  for (int i = 0; i < 4; ++i) o[i] = tile[c + i][r];
  *(ushortx4*)(WT + (n0 + r) * EMB + k0 + c) = o;
}

// shared k-loop body for the 128x128 GEMMs
#define GEMM_KLOOP(OP1, OP2)                                                 \
    for (int kk = 0; kk < 64; kk += 32) {                                    \
      short8 a[4], b[4];                                                     \
      _Pragma("unroll")                                                      \
      for (int i = 0; i < 4; ++i)                                            \
        a[i] = *(const short8*)(As + (wr * 64 + i * 16 + ln) * 64 + kk + g * 8); \
      _Pragma("unroll")                                                      \
      for (int j = 0; j < 4; ++j)                                            \
        b[j] = *(const short8*)(Bs + (wc * 64 + j * 16 + ln) * 64 + kk + g * 8); \
      _Pragma("unroll")                                                      \
      for (int i = 0; i < 4; ++i)                                            \
        _Pragma("unroll")                                                    \
        for (int j = 0; j < 4; ++j)                                          \
          acc[i][j] = mfma16(OP1, OP2, acc[i][j]);                           \
    }

#define GEMM_STAGE(Aptr, Bptr, kt_, buf_)                                    \
    do {                                                                     \
      const int kb_ = (kt_) * 64;                                            \
      _Pragma("unroll")                                                      \
      for (int it = 0; it < 4; ++it) {                                       \
        const int chunk = w * 4 + it;                                        \
        const int lin = chunk * 64 + l;                                      \
        const int row = lin >> 3, col = (lin & 7) * 8;                       \
        gload16(Aptr + (m0 + row) * EMB + kb_ + col,                         \
                (char*)&AsB[buf_][0] + chunk * 1024);                        \
        gload16(Bptr + (n0 + row) * EMB + kb_ + col,                         \
                (char*)&BsB[buf_][0] + chunk * 1024);                        \
      }                                                                      \
    } while (0)

// ---------------------------------------------------------------------------
// GEMM: C[m][n] = Xb[m][k] * WT[n][k]^T + bias.  (unchanged from r13)
// ---------------------------------------------------------------------------
__global__ __launch_bounds__(256) void gemm_qkv_kernel(
    const unsigned short* __restrict__ Xb,
    const unsigned short* __restrict__ W0, const unsigned short* __restrict__ W1,
    const unsigned short* __restrict__ W2,
    const float* __restrict__ b0, const float* __restrict__ b1,
    const float* __restrict__ b2,
    unsigned short* __restrict__ Qo, unsigned short* __restrict__ Ko,
    unsigned short* __restrict__ Vo) {
  __shared__ __align__(16) unsigned short AsB[2][128 * 64];
  __shared__ __align__(16) unsigned short BsB[2][128 * 64];
  const int z = blockIdx.z;
  const unsigned short* Wt = (z == 0) ? W0 : ((z == 1) ? W1 : W2);
  const float* bias = (z == 0) ? b0 : ((z == 1) ? b1 : b2);
  const bool sw = (z != 2);
  const int m0 = blockIdx.y * 128, n0 = blockIdx.x * 128;
  const int tid = threadIdx.x, l = tid & 63, w = tid >> 6;
  const int g = l >> 4, ln = l & 15;
  const int wr = w >> 1, wc = w & 1;

  f32x4 acc[4][4];
  #pragma unroll
  for (int i = 0; i < 4; ++i)
    #pragma unroll
    for (int j = 0; j < 4; ++j) acc[i][j] = (f32x4){0.f, 0.f, 0.f, 0.f};

  GEMM_STAGE(Xb, Wt, 0, 0);
  #pragma unroll 1
  for (int kt = 0; kt < 16; ++kt) {
    const int cur = kt & 1;
    if (kt + 1 < 16) {
      GEMM_STAGE(Xb, Wt, kt + 1, cur ^ 1);
      asm volatile("s_waitcnt vmcnt(8)" ::: "memory");
    } else {
      asm volatile("s_waitcnt vmcnt(0)" ::: "memory");
    }
    __builtin_amdgcn_s_barrier();
    const unsigned short* As = &AsB[cur][0];
    const unsigned short* Bs = &BsB[cur][0];
    if (sw) {
      GEMM_KLOOP(b[j], a[i])
    } else {
      GEMM_KLOOP(a[i], b[j])
    }
    asm volatile("" ::: "memory");
    __builtin_amdgcn_s_barrier();
  }

  const int mb = m0 + wr * 64, nb = n0 + wc * 64;
  if (sw) {
    unsigned short* dst = (z == 0) ? Qo : Ko;
    const float osc = (z == 0) ? QSCALE : 1.0f;
    #pragma unroll
    for (int j = 0; j < 4; ++j) {
      const int n = nb + j * 16 + 4 * g;
      floatx4 bv_ = *(const floatx4*)(bias + n);
      const int h = n >> 6, d = n & 63;
      #pragma unroll
      for (int i = 0; i < 4; ++i) {
        const int m = mb + i * 16 + ln;
        const int bb = m >> 11, ss = m & 2047;
        ushortx4 o;
        #pragma unroll
        for (int e = 0; e < 4; ++e) o[e] = bf16u((acc[i][j][e] + bv_[e]) * osc);
        *(ushortx4*)(dst + ((bb * NH + h) * SEQ + ss) * HD + d) = o;
      }
    }
  } else {
    #pragma unroll
    for (int j = 0; j < 4; ++j) {
      const int n = nb + j * 16 + ln;
      const float bgain = bias[n];
      const int h = n >> 6, d = n & 63;
      #pragma unroll
      for (int i = 0; i < 4; ++i) {
        const int mf = mb + i * 16 + 4 * g;
        const int bb = mf >> 11, ss = mf & 2047;
        ushortx4 o;
        #pragma unroll
        for (int e = 0; e < 4; ++e) o[e] = bf16u(acc[i][j][e] + bgain);
        *(ushortx4*)(Vo + ((bb * NH + h) * HD + d) * SEQ + ss) = o;
      }
    }
  }
}

// ---------------------------------------------------------------------------
// Causal flash attention, 32x32x16 MFMA (r11-verified layout) + KV-split.
// Block = 4 waves (256 thr), QBLK=128 (32 q-rows/wave), KVBLK=128 dbuf (64KB).
// Grid 1024: j = id>>8 (dispatch batch), slot = id&255, bh = slot&31,
// p = slot>>5.  j<2 -> T = 15-p (long tiles, dispatched first); j>=2 -> T = p.
// half = j&1.  na = (T+2)>>1; half0 does kt in [0,na), half1 [na,T+1).
// Each block writes unnormalized partial acc (bf16) to Opart[bh][T][half]
// plus per-q-row (m,l) to mlbuf.  Empty half (T=0,h1) writes m=-1e30,l=0,acc=0.
// ---------------------------------------------------------------------------
__global__ __launch_bounds__(256) void attn_kernel(
    const unsigned short* __restrict__ Q, const unsigned short* __restrict__ K,
    const unsigned short* __restrict__ Vt,
    unsigned short* __restrict__ Opart, float* __restrict__ mlbuf) {
  __shared__ __align__(16) unsigned short Kt[2][128 * 64];
  __shared__ __align__(16) unsigned short Vl[2][64 * 128];
  const int id = blockIdx.x;
  const int j = id >> 8;                        // dispatch batch 0..3
  const int slot = id & 255;
  const int bh = slot & 31;
  const int p = slot >> 5;                      // 0..7
  const int T = (j < 2) ? (15 - p) : p;
  const int half = j & 1;
  const int na = (T + 2) >> 1;
  const int kt0 = half ? na : 0;
  const int kt1 = half ? (T + 1) : na;
  const int len = kt1 - kt0;
  const int tid = threadIdx.x, l = tid & 63, w = tid >> 6;   // w = 0..3
  const int q32 = l & 31;
  const int hi = l >> 5;
  const size_t baseQK = (size_t)bh * SEQ * HD;   // [s][d]
  const size_t baseV = (size_t)bh * HD * SEQ;    // [d][s]

  // staging constants: K chunk = 8 rows x 128B; V chunk = 4 rows x 256B
  const int krw = l >> 3;                         // 0..7
  const int kcg = (l & 7) ^ (l >> 3);             // swizzled 16B group
  const int vrw = l >> 4;                         // 0..3

  const int qw = T * 128 + w * 32;

  float m_run = -1e30f, l_run = 0.f;
  f32x16 acc[2];
  #pragma unroll
  for (int dh = 0; dh < 2; ++dh)
    #pragma unroll
    for (int r = 0; r < 16; ++r) acc[dh][r] = 0.f;

  if (len > 0) {
    // stage tile kt0 into buf 0 (8 gload16 per wave: 4 K + 4 V chunks)
    {
      const size_t kof = (size_t)kt0 * 128;
      #pragma unroll
      for (int i = 0; i < 4; ++i) {
        const int c = 4 * w + i;
        gload16(K + baseQK + (kof + 8 * c + krw) * HD + kcg * 8,
                (char*)&Kt[0][0] + c * 1024);
        const int vr = 4 * c + vrw;
        const int vcg = (l & 15) ^ (vr & 15);
        gload16(Vt + baseV + (size_t)vr * SEQ + kof + vcg * 8,
                (char*)&Vl[0][0] + c * 1024);
      }
    }

    // Q fragments (B-operand): qf[ds] = Q[qw+q32][ds*16 + 8*hi + e]
    const int qrow = qw + q32;
    short8 qf[4];
    #pragma unroll
    for (int ds = 0; ds < 4; ++ds)
      qf[ds] = *(const short8*)(Q + baseQK + (size_t)qrow * HD + ds * 16 + hi * 8);

    #pragma unroll 1
    for (int kt = kt0; kt < kt1; ++kt) {
      const int cur = (kt - kt0) & 1;
      const bool has_next = (kt + 1 < kt1);
      if (has_next) {
        const int nxt = cur ^ 1;
        const size_t kof = (size_t)(kt + 1) * 128;
        #pragma unroll
        for (int i = 0; i < 4; ++i) {
          const int c = 4 * w + i;
          gload16(K + baseQK + (kof + 8 * c + krw) * HD + kcg * 8,
                  (char*)&Kt[nxt][0] + c * 1024);
          const int vr = 4 * c + vrw;
          const int vcg = (l & 15) ^ (vr & 15);
          gload16(Vt + baseV + (size_t)vr * SEQ + kof + vcg * 8,
                  (char*)&Vl[nxt][0] + c * 1024);
        }
        asm volatile("s_waitcnt vmcnt(8)" ::: "memory");
      } else {
        asm volatile("s_waitcnt vmcnt(0)" ::: "memory");
      }
      __builtin_amdgcn_s_barrier();

      const bool last = (kt == T);

      // ---- QK^T: sv[kj] covers keys kt*128 + kj*32 + crow(reg,hi) ----
      f32x16 sv[4];
      #pragma unroll
      for (int kj = 0; kj < 4; ++kj)
        #pragma unroll
        for (int r = 0; r < 16; ++r) sv[kj][r] = -1e30f;

      __builtin_amdgcn_s_setprio(1);
      #pragma unroll
      for (int kj = 0; kj < 4; ++kj) {
        if (!last || kj <= w) {
          f32x16 t;
          #pragma unroll
          for (int r = 0; r < 16; ++r) t[r] = 0.f;
          #pragma unroll
          for (int ds = 0; ds < 4; ++ds) {
            short8 kf = *(const short8*)(
                &Kt[cur][(kj * 32 + q32) * 64 + (((ds * 2 + hi) ^ (l & 7)) * 8)]);
            t = mfma32(kf, qf[ds], t);
          }
          if (last && kj == w) {
            #pragma unroll
            for (int r = 0; r < 16; ++r) {
              const int crow = (r & 3) + 8 * (r >> 2) + 4 * hi;
              sv[kj][r] = (crow <= q32) ? t[r] : -1e30f;
            }
          } else {
            sv[kj] = t;
          }
        }
      }
      __builtin_amdgcn_s_setprio(0);

      // ---- online softmax (exp2), q-column local: 1 shfl per reduce ----
      float tm = -1e30f;
      #pragma unroll
      for (int kj = 0; kj < 4; ++kj)
        #pragma unroll
        for (int r = 0; r < 16; ++r) tm = fmaxf(tm, sv[kj][r]);
      tm = fmaxf(tm, __shfl_xor(tm, 32));
      const float nm = fmaxf(m_run, tm);
      const float al = exp2f(m_run - nm);
      m_run = nm;

      // rescale acc (q = crow domain): broadcast al from lane crow
      #pragma unroll
      for (int r = 0; r < 16; ++r) {
        const int crb = (r & 3) + 8 * (r >> 2);
        const float ar = __shfl(al, crb + 4 * hi);
        acc[0][r] *= ar;
        acc[1][r] *= ar;
      }

      // ---- P = exp2(S-nm); pack into PV A-fragments (cvt_pk + permlane) ----
      float rs = 0.f;
      short8 pa[8];
      #pragma unroll
      for (int kj = 0; kj < 4; ++kj) {
        if (!last || kj <= w) {
          float pv[16];
          #pragma unroll
          for (int r = 0; r < 16; ++r) {
            pv[r] = exp2f(sv[kj][r] - nm);
            rs += pv[r];
          }
          unsigned A0 = pkbf(pv[0], pv[1]);
          unsigned B0 = pkbf(pv[2], pv[3]);
          unsigned C0 = pkbf(pv[4], pv[5]);
          unsigned D0 = pkbf(pv[6], pv[7]);
          plswap(A0, C0);
          plswap(B0, D0);
          uintx4 u0;
          u0[0] = A0; u0[1] = B0; u0[2] = C0; u0[3] = D0;
          pa[2 * kj] = __builtin_bit_cast(short8, u0);
          unsigned A1 = pkbf(pv[8], pv[9]);
          unsigned B1 = pkbf(pv[10], pv[11]);
          unsigned C1 = pkbf(pv[12], pv[13]);
          unsigned D1 = pkbf(pv[14], pv[15]);
          plswap(A1, C1);
          plswap(B1, D1);
          uintx4 u1;
          u1[0] = A1; u1[1] = B1; u1[2] = C1; u1[3] = D1;
          pa[2 * kj + 1] = __builtin_bit_cast(short8, u1);
        }
      }
      rs += __shfl_xor(rs, 32);
      l_run = l_run * al + rs;

      // ---- PV: acc[dh] += P x V ----
      const int smax = last ? (2 * w + 2) : 8;
      __builtin_amdgcn_s_setprio(1);
      #pragma unroll
      for (int dh = 0; dh < 2; ++dh) {
        #pragma unroll
        for (int s = 0; s < 8; ++s) {
          if (s < smax) {
            short8 vb = *(const short8*)(
                &Vl[cur][(32 * dh + q32) * 128 + (((s * 2 + hi) ^ (l & 15)) * 8)]);
            acc[dh] = mfma32(pa[s], vb, acc[dh]);
          }
        }
      }
      __builtin_amdgcn_s_setprio(0);

      asm volatile("" ::: "memory");
      __builtin_amdgcn_s_barrier();
    }
  }

  // ---- partial epilogue: unnormalized acc (bf16) + (m,l) per q-row ----
  const int blk = bh * 16 + T;
  const int pbase = ((blk * 2 + half) * 128) * 64;
  #pragma unroll
  for (int dh = 0; dh < 2; ++dh) {
    #pragma unroll
    for (int r = 0; r < 16; ++r) {
      const int ql = w * 32 + (r & 3) + 8 * (r >> 2) + 4 * hi;
      Opart[pbase + ql * 64 + 32 * dh + q32] = bf16u(acc[dh][r]);
    }
  }
  if (l < 32) {
    const int mb = blk * 512 + half * 256;
    mlbuf[mb + w * 32 + q32] = m_run;
    mlbuf[mb + 128 + w * 32 + q32] = l_run;
  }
}

// ---------------------------------------------------------------------------
// Combine: merge the two KV-halves' partials into Ao (bf16 [b][s][h*64+d]).
// O = (w0*acc0 + w1*acc1) / (w0*l0 + w1*l1), w_i = exp2(m_i - max(m0,m1)).
// ---------------------------------------------------------------------------
__global__ __launch_bounds__(256) void combine_kernel(
    const unsigned short* __restrict__ Opart, const float* __restrict__ mlbuf,
    unsigned short* __restrict__ Ao) {
  const int blk = blockIdx.x;          // bh*16 + T
  const int bh = blk >> 4, T = blk & 15;
  const int h = bh & 15, b = bh >> 4;
  const int t = threadIdx.x;
  const int d0 = (t & 15) * 4;
  const int p0 = (blk * 2 + 0) * 128 * 64;
  const int p1 = (blk * 2 + 1) * 128 * 64;
  #pragma unroll 1
  for (int pass = 0; pass < 8; ++pass) {
    const int ql = pass * 16 + (t >> 4);
    const float m0 = mlbuf[blk * 512 + ql];
    const float l0 = mlbuf[blk * 512 + 128 + ql];
    const float m1 = mlbuf[blk * 512 + 256 + ql];
    const float l1 = mlbuf[blk * 512 + 384 + ql];
    const float m = fmaxf(m0, m1);
    const float w0 = exp2f(m0 - m);
    const float w1 = exp2f(m1 - m);
    const float inv = 1.f / (w0 * l0 + w1 * l1);
    ushortx4 a0 = *(const ushortx4*)(Opart + p0 + ql * 64 + d0);
    ushortx4 a1 = *(const ushortx4*)(Opart + p1 + ql * 64 + d0);
    ushortx4 o;
    #pragma unroll
    for (int e = 0; e < 4; ++e)
      o[e] = bf16u((w0 * bf2f(a0[e]) + w1 * bf2f(a1[e])) * inv);
    const int q = T * 128 + ql;
    *(ushortx4*)(Ao + ((size_t)(b * SEQ + q)) * EMB + h * HD + d0) = o;
  }
}

// ---------------------------------------------------------------------------
// Output projection: fp32 out = AttnOut(bf16) @ Wo + bo.  (unchanged r13)
// ---------------------------------------------------------------------------
__global__ __launch_bounds__(256) void gemm_o_kernel(
    const unsigned short* __restrict__ Ab, const unsigned short* __restrict__ Wt,
    const float* __restrict__ bias, float* __restrict__ out) {
  __shared__ __align__(16) unsigned short AsB[2][128 * 64];
  __shared__ __align__(16) unsigned short BsB[2][128 * 64];
  const int m0 = blockIdx.y * 128, n0 = blockIdx.x * 128;
  const int tid = threadIdx.x, l = tid & 63, w = tid >> 6;
  const int g = l >> 4, ln = l & 15;
  const int wr = w >> 1, wc = w & 1;

  f32x4 acc[4][4];
  #pragma unroll
  for (int i = 0; i < 4; ++i)
    #pragma unroll
    for (int j = 0; j < 4; ++j) acc[i][j] = (f32x4){0.f, 0.f, 0.f, 0.f};

  GEMM_STAGE(Ab, Wt, 0, 0);
  #pragma unroll 1
  for (int kt = 0; kt < 16; ++kt) {
    const int cur = kt & 1;
    if (kt + 1 < 16) {
      GEMM_STAGE(Ab, Wt, kt + 1, cur ^ 1);
      asm volatile("s_waitcnt vmcnt(8)" ::: "memory");
    } else {
      asm volatile("s_waitcnt vmcnt(0)" ::: "memory");
    }
    __builtin_amdgcn_s_barrier();
    const unsigned short* As = &AsB[cur][0];
    const unsigned short* Bs = &BsB[cur][0];
    GEMM_KLOOP(b[j], a[i])
    asm volatile("" ::: "memory");
    __builtin_amdgcn_s_barrier();
  }

  const int mb = m0 + wr * 64, nb = n0 + wc * 64;
  #pragma unroll
  for (int j = 0; j < 4; ++j) {
    const int n = nb + j * 16 + 4 * g;
    floatx4 bv_ = *(const floatx4*)(bias + n);
    #pragma unroll
    for (int i = 0; i < 4; ++i) {
      const int m = mb + i * 16 + ln;
      floatx4 o = acc[i][j] + bv_;
      *(floatx4*)(out + (size_t)m * EMB + n) = o;
    }
  }
}

// ---------------------------------------------------------------------------
extern "C" void kernel_launch(void* const* d_in, const int* in_sizes, int n_in,
                              void* d_out, int out_size, void* d_ws, size_t ws_size,
                              hipStream_t stream) {
  const float* x  = (const float*)d_in[0];
  const float* Wq = (const float*)d_in[1];
  const float* bq = (const float*)d_in[2];
  const float* Wk = (const float*)d_in[3];
  const float* bk = (const float*)d_in[4];
  const float* Wv = (const float*)d_in[5];
  const float* bv = (const float*)d_in[6];
  const float* Wo = (const float*)d_in[7];
  const float* bo = (const float*)d_in[8];
  float* out = (float*)d_out;

  char* ws = (char*)d_ws;
  unsigned short* Xb  = (unsigned short*)(ws);              // 8 MB  [4096][1024]
  unsigned short* WqT = (unsigned short*)(ws + 8388608);    // 2 MB each [n][k]
  unsigned short* WkT = (unsigned short*)(ws + 10485760);
  unsigned short* WvT = (unsigned short*)(ws + 12582912);
  unsigned short* WoT = (unsigned short*)(ws + 14680064);
  unsigned short* Qb  = (unsigned short*)(ws + 16777216);   // 8 MB [b][h][s][d]
  unsigned short* Kb  = (unsigned short*)(ws + 25165824);   // 8 MB [b][h][s][d]
  unsigned short* Vtb = (unsigned short*)(ws + 33554432);   // 8 MB [b][h][d][s]
  unsigned short* Ao  = Xb;   // attention output (combine) reuses Xb
  // KV-split partials: d_out (16 MB, fully overwritten by gemm_o);
  // m/l: WqT region (dead after gemm_qkv; 1 MB of its 2 MB).
  unsigned short* Opart = (unsigned short*)d_out;
  float* mlbuf = (float*)WqT;

  hipLaunchKernelGGL(cvt_all_kernel, dim3(32, 32, 5), dim3(256), 0, stream,
                     x, Xb, Wq, Wk, Wv, Wo, WqT, WkT, WvT, WoT);
  hipLaunchKernelGGL(gemm_qkv_kernel, dim3(8, 32, 3), dim3(256), 0, stream,
                     Xb, WqT, WkT, WvT, bq, bk, bv, Qb, Kb, Vtb);
  hipLaunchKernelGGL(attn_kernel, dim3(1024), dim3(256), 0, stream,
                     Qb, Kb, Vtb, Opart, mlbuf);
  hipLaunchKernelGGL(combine_kernel, dim3(512), dim3(256), 0, stream,
                     Opart, mlbuf, Ao);
  hipLaunchKernelGGL(gemm_o_kernel, dim3(8, 32), dim3(256), 0, stream,
                     Ao, WoT, bo, out);
}

// Round 15
// 158.592 us; speedup vs baseline: 1.0300x; 1.0300x over previous
//
#include <hip/hip_runtime.h>

// ---------------------------------------------------------------------------
// Causal MHA block: QKV proj (bf16 MFMA) -> flash attention -> out proj.
// B=2, S=2048, E=1024, H=16, D=64.
// r15 = r13 (measured best, 158.6 us): merged converts + 2-phase GEMMs +
// r9 attention (16x16 MFMA, 8-wave QBLK=128/KVBLK=128, complementary pairing).
// ---------------------------------------------------------------------------

#define EMB 1024
#define SEQ 2048
#define NB 2
#define NH 16
#define HD 64

// 0.125 (1/sqrt(64)) * log2(e): QK logits land in exp2 domain
#define QSCALE 0.18033688011112042f

typedef float f32x4 __attribute__((ext_vector_type(4)));
typedef float floatx4 __attribute__((ext_vector_type(4)));
typedef short short8 __attribute__((ext_vector_type(8)));
typedef __bf16 bf16x8 __attribute__((ext_vector_type(8)));
typedef __bf16 bf16x2 __attribute__((ext_vector_type(2)));
typedef unsigned short ushortx4 __attribute__((ext_vector_type(4)));
typedef unsigned int uintx4 __attribute__((ext_vector_type(4)));

// native f32->bf16 (RNE, compiler emits v_cvt_pk_bf16_f32 for pairs)
__device__ __forceinline__ unsigned short bf16u(float f) {
  __bf16 h = (__bf16)f;
  return __builtin_bit_cast(unsigned short, h);
}

__device__ __forceinline__ unsigned pkbf(float lo, float hi) {
  bf16x2 v;
  v[0] = (__bf16)lo;
  v[1] = (__bf16)hi;
  return __builtin_bit_cast(unsigned, v);
}

__device__ __forceinline__ f32x4 mfma16(short8 a, short8 b, f32x4 c) {
  return __builtin_amdgcn_mfma_f32_16x16x32_bf16(
      __builtin_bit_cast(bf16x8, a), __builtin_bit_cast(bf16x8, b), c, 0, 0, 0);
}

// async global -> LDS, 16B per lane; lds dest is wave-uniform base + lane*16
__device__ __forceinline__ void gload16(const void* g, void* lds) {
  __builtin_amdgcn_global_load_lds(
      (const __attribute__((address_space(1))) unsigned int*)g,
      (__attribute__((address_space(3))) unsigned int*)lds, 16, 0, 0);
}

// ---------------------------------------------------------------------------
// Merged converts: z<4 -> fp32 W[k][n] -> bf16 WT[n][k] (32x32 LDS transpose);
// z==4 -> fp32 x -> bf16 (16 elements/thread, float4-coalesced).
// ---------------------------------------------------------------------------
__global__ __launch_bounds__(256) void cvt_all_kernel(
    const float* __restrict__ x, unsigned short* __restrict__ Xb,
    const float* __restrict__ W0, const float* __restrict__ W1,
    const float* __restrict__ W2, const float* __restrict__ W3,
    unsigned short* __restrict__ T0, unsigned short* __restrict__ T1,
    unsigned short* __restrict__ T2, unsigned short* __restrict__ T3) {
  const int z = blockIdx.z;
  const int t = threadIdx.x;
  if (z == 4) {
    // x convert: 1024 virtual blocks of 4096 elements
    const int blin = blockIdx.y * 32 + blockIdx.x;
    const int base = blin * 4096 + t * 4;
    #pragma unroll
    for (int c = 0; c < 4; ++c) {
      const int idx = base + c * 1024;
      floatx4 v = *(const floatx4*)(x + idx);
      ushortx4 o;
      #pragma unroll
      for (int i = 0; i < 4; ++i) o[i] = bf16u(v[i]);
      *(ushortx4*)(Xb + idx) = o;
    }
    return;
  }
  __shared__ unsigned short tile[32][33];
  const float* W = (z == 0) ? W0 : (z == 1) ? W1 : (z == 2) ? W2 : W3;
  unsigned short* WT = (z == 0) ? T0 : (z == 1) ? T1 : (z == 2) ? T2 : T3;
  const int k0 = blockIdx.x * 32, n0 = blockIdx.y * 32;
  const int r = t >> 3, c = (t & 7) * 4;
  floatx4 v = *(const floatx4*)(W + (k0 + r) * EMB + n0 + c);
  #pragma unroll
  for (int i = 0; i < 4; ++i) tile[r][c + i] = bf16u(v[i]);
  __syncthreads();
  ushortx4 o;
  #pragma unroll
  for (int i = 0; i < 4; ++i) o[i] = tile[c + i][r];
  *(ushortx4*)(WT + (n0 + r) * EMB + k0 + c) = o;
}

// shared k-loop body for the 128x128 GEMMs; OP1's tile index lands on the
// accumulator reg axis (4g+e), OP2's on the lane-col axis (ln).
#define GEMM_KLOOP(OP1, OP2)                                                 \
    for (int kk = 0; kk < 64; kk += 32) {                                    \
      short8 a[4], b[4];                                                     \
      _Pragma("unroll")                                                      \
      for (int i = 0; i < 4; ++i)                                            \
        a[i] = *(const short8*)(As + (wr * 64 + i * 16 + ln) * 64 + kk + g * 8); \
      _Pragma("unroll")                                                      \
      for (int j = 0; j < 4; ++j)                                            \
        b[j] = *(const short8*)(Bs + (wc * 64 + j * 16 + ln) * 64 + kk + g * 8); \
      _Pragma("unroll")                                                      \
      for (int i = 0; i < 4; ++i)                                            \
        _Pragma("unroll")                                                    \
        for (int j = 0; j < 4; ++j)                                          \
          acc[i][j] = mfma16(OP1, OP2, acc[i][j]);                           \
    }

#define GEMM_STAGE(Aptr, Bptr, kt_, buf_)                                    \
    do {                                                                     \
      const int kb_ = (kt_) * 64;                                            \
      _Pragma("unroll")                                                      \
      for (int it = 0; it < 4; ++it) {                                       \
        const int chunk = w * 4 + it;                                        \
        const int lin = chunk * 64 + l;                                      \
        const int row = lin >> 3, col = (lin & 7) * 8;                       \
        gload16(Aptr + (m0 + row) * EMB + kb_ + col,                         \
                (char*)&AsB[buf_][0] + chunk * 1024);                        \
        gload16(Bptr + (n0 + row) * EMB + kb_ + col,                         \
                (char*)&BsB[buf_][0] + chunk * 1024);                        \
      }                                                                      \
    } while (0)

// ---------------------------------------------------------------------------
// GEMM: C[m][n] = Xb[m][k] * WT[n][k]^T + bias.  128x128 tile, BK=64, 4 waves,
// 2-phase double-buffered staging (counted vmcnt(8), never 0 mid-loop).
// z=0 -> Q[b][h][s][d] (pre-scaled by QSCALE), z=1 -> K[b][h][s][d]:
//   operand-swapped MFMA so regs walk d -> packed ushortx4 stores.
// z=2 -> Vt[b][h][d][s]: normal order so regs walk s -> packed stores.
// ---------------------------------------------------------------------------
__global__ __launch_bounds__(256) void gemm_qkv_kernel(
    const unsigned short* __restrict__ Xb,
    const unsigned short* __restrict__ W0, const unsigned short* __restrict__ W1,
    const unsigned short* __restrict__ W2,
    const float* __restrict__ b0, const float* __restrict__ b1,
    const float* __restrict__ b2,
    unsigned short* __restrict__ Qo, unsigned short* __restrict__ Ko,
    unsigned short* __restrict__ Vo) {
  __shared__ __align__(16) unsigned short AsB[2][128 * 64];
  __shared__ __align__(16) unsigned short BsB[2][128 * 64];
  const int z = blockIdx.z;
  const unsigned short* Wt = (z == 0) ? W0 : ((z == 1) ? W1 : W2);
  const float* bias = (z == 0) ? b0 : ((z == 1) ? b1 : b2);
  const bool sw = (z != 2);
  const int m0 = blockIdx.y * 128, n0 = blockIdx.x * 128;
  const int tid = threadIdx.x, l = tid & 63, w = tid >> 6;
  const int g = l >> 4, ln = l & 15;
  const int wr = w >> 1, wc = w & 1;

  f32x4 acc[4][4];
  #pragma unroll
  for (int i = 0; i < 4; ++i)
    #pragma unroll
    for (int j = 0; j < 4; ++j) acc[i][j] = (f32x4){0.f, 0.f, 0.f, 0.f};

  GEMM_STAGE(Xb, Wt, 0, 0);
  #pragma unroll 1
  for (int kt = 0; kt < 16; ++kt) {
    const int cur = kt & 1;
    if (kt + 1 < 16) {
      GEMM_STAGE(Xb, Wt, kt + 1, cur ^ 1);
      asm volatile("s_waitcnt vmcnt(8)" ::: "memory");
    } else {
      asm volatile("s_waitcnt vmcnt(0)" ::: "memory");
    }
    __builtin_amdgcn_s_barrier();
    const unsigned short* As = &AsB[cur][0];
    const unsigned short* Bs = &BsB[cur][0];
    if (sw) {
      GEMM_KLOOP(b[j], a[i])
    } else {
      GEMM_KLOOP(a[i], b[j])
    }
    asm volatile("" ::: "memory");
    __builtin_amdgcn_s_barrier();
  }

  const int mb = m0 + wr * 64, nb = n0 + wc * 64;
  if (sw) {
    unsigned short* dst = (z == 0) ? Qo : Ko;
    const float osc = (z == 0) ? QSCALE : 1.0f;
    #pragma unroll
    for (int j = 0; j < 4; ++j) {
      const int n = nb + j * 16 + 4 * g;
      floatx4 bv_ = *(const floatx4*)(bias + n);
      const int h = n >> 6, d = n & 63;
      #pragma unroll
      for (int i = 0; i < 4; ++i) {
        const int m = mb + i * 16 + ln;
        const int bb = m >> 11, ss = m & 2047;
        ushortx4 o;
        #pragma unroll
        for (int e = 0; e < 4; ++e) o[e] = bf16u((acc[i][j][e] + bv_[e]) * osc);
        *(ushortx4*)(dst + ((bb * NH + h) * SEQ + ss) * HD + d) = o;
      }
    }
  } else {
    #pragma unroll
    for (int j = 0; j < 4; ++j) {
      const int n = nb + j * 16 + ln;
      const float bgain = bias[n];
      const int h = n >> 6, d = n & 63;
      #pragma unroll
      for (int i = 0; i < 4; ++i) {
        const int mf = mb + i * 16 + 4 * g;
        const int bb = mf >> 11, ss = mf & 2047;
        ushortx4 o;
        #pragma unroll
        for (int e = 0; e < 4; ++e) o[e] = bf16u(acc[i][j][e] + bgain);
        *(ushortx4*)(Vo + ((bb * NH + h) * HD + d) * SEQ + ss) = o;
      }
    }
  }
}

// ---------------------------------------------------------------------------
// Causal flash attention (r9 known-good: 66.5 us).  8 waves, QBLK=128
// (16 q-rows/wave), KVBLK=128 double-buffered (64KB LDS).  Grid 512 1-D:
// bh = id&31 (4 bh per XCD slot), complementary T-pairing:
// grp = id>>5; T = grp<8 ? 15-grp : grp-8  (every CU-pair sums to 17 iters).
// K LDS [128][64] (8-group XOR swizzle); V LDS [64][128] (16-group XOR
// swizzle).  kt<T: 8 full j-fragments; kt==T: jmax=w, triangle at j==w.
// ---------------------------------------------------------------------------
__global__ __launch_bounds__(512) void attn_kernel(
    const unsigned short* __restrict__ Q, const unsigned short* __restrict__ K,
    const unsigned short* __restrict__ Vt, unsigned short* __restrict__ O) {
  __shared__ __align__(16) unsigned short Kt[2][128 * 64];
  __shared__ __align__(16) unsigned short Vl[2][64 * 128];
  const int id = blockIdx.x;
  const int bh = id & 31;
  const int grp = id >> 5;
  const int T = (grp < 8) ? (15 - grp) : (grp - 8);
  const int h = bh & 15, b = bh >> 4;
  const int tid = threadIdx.x, l = tid & 63, w = tid >> 6;   // w = 0..7
  const int g = l >> 4, ln = l & 15;
  const size_t baseQK = (size_t)bh * SEQ * HD;   // [s][d]
  const size_t baseV = (size_t)bh * HD * SEQ;    // [d][s]
  const int xr = ln & 7;                          // K read-side swizzle xor
  const int srcA = ((g & 1) << 5) + ln;           // P-shuffle source lanes
  const int srcB = srcA + 16;
  const bool hi = (g >> 1) != 0;

  // K staging: chunks 2w,2w+1 of 16 (1KB = 8 rows x 128B)
  const int kr0 = (2 * w) * 8 + (l >> 3), kr1 = (2 * w + 1) * 8 + (l >> 3);
  const int kc0 = (l & 7) ^ (kr0 & 7), kc1 = (l & 7) ^ (kr1 & 7);
  // V staging: chunks 2w,2w+1 of 16 (1KB = 4 rows x 256B)
  const int vr0 = (2 * w) * 4 + (l >> 4), vr1 = (2 * w + 1) * 4 + (l >> 4);
  const int vc0 = (l & 15) ^ (vr0 & 15), vc1 = (l & 15) ^ (vr1 & 15);

  const int nkt = T + 1;
  const int qw = T * 128 + w * 16;

  // stage kt=0 into buf 0 (4 gload_lds per wave)
  gload16(K + baseQK + (size_t)kr0 * HD + kc0 * 8,
          (char*)&Kt[0][0] + (2 * w) * 1024);
  gload16(K + baseQK + (size_t)kr1 * HD + kc1 * 8,
          (char*)&Kt[0][0] + (2 * w + 1) * 1024);
  gload16(Vt + baseV + (size_t)vr0 * SEQ + vc0 * 8,
          (char*)&Vl[0][0] + (2 * w) * 1024);
  gload16(Vt + baseV + (size_t)vr1 * SEQ + vc1 * 8,
          (char*)&Vl[0][0] + (2 * w + 1) * 1024);

  // Q fragments (B-operand: col = q = ln, contraction d)
  const int qrow = qw + ln;
  short8 qf0 = *(const short8*)(Q + baseQK + (size_t)qrow * HD + g * 8);
  short8 qf1 = *(const short8*)(Q + baseQK + (size_t)qrow * HD + 32 + g * 8);

  float m_run = -1e30f, l_run = 0.f;
  f32x4 acc[4];
  #pragma unroll
  for (int dj = 0; dj < 4; ++dj) acc[dj] = (f32x4){0.f, 0.f, 0.f, 0.f};

  #pragma unroll 1
  for (int kt = 0; kt < nkt; ++kt) {
    const int cur = kt & 1;
    const bool has_next = (kt + 1 < nkt);
    if (has_next) {  // prefetch next 128-key tile into other buffer
      const int nxt = cur ^ 1;
      const size_t kof = (size_t)(kt + 1) * 128;
      gload16(K + baseQK + (kof + kr0) * HD + kc0 * 8,
              (char*)&Kt[nxt][0] + (2 * w) * 1024);
      gload16(K + baseQK + (kof + kr1) * HD + kc1 * 8,
              (char*)&Kt[nxt][0] + (2 * w + 1) * 1024);
      gload16(Vt + baseV + (size_t)vr0 * SEQ + kof + vc0 * 8,
              (char*)&Vl[nxt][0] + (2 * w) * 1024);
      gload16(Vt + baseV + (size_t)vr1 * SEQ + kof + vc1 * 8,
              (char*)&Vl[nxt][0] + (2 * w + 1) * 1024);
      asm volatile("s_waitcnt vmcnt(4)" ::: "memory");
    } else {
      asm volatile("s_waitcnt vmcnt(0)" ::: "memory");
    }
    __builtin_amdgcn_s_barrier();

    const bool last = (kt == T);
    const int jmax = last ? w : 7;

    // QK^T swapped: sv[j][e] = S[q=qw+ln][k = kt*128 + j*16 + 4g+e]
    f32x4 sv[8];
    #pragma unroll
    for (int j = 0; j < 8; ++j)
      sv[j] = (f32x4){-1e30f, -1e30f, -1e30f, -1e30f};
    __builtin_amdgcn_s_setprio(1);
    #pragma unroll
    for (int j = 0; j < 8; ++j) {
      if (j <= jmax) {
        f32x4 t = (f32x4){0.f, 0.f, 0.f, 0.f};
        short8 kf0 = *(const short8*)(
            &Kt[cur][(j * 16 + ln) * 64 + ((g ^ xr) * 8)]);
        t = mfma16(kf0, qf0, t);
        short8 kf1 = *(const short8*)(
            &Kt[cur][(j * 16 + ln) * 64 + (((4 + g) ^ xr) * 8)]);
        t = mfma16(kf1, qf1, t);
        if (last && j == w) {               // triangle tile
          #pragma unroll
          for (int e = 0; e < 4; ++e)
            sv[j][e] = (4 * g + e <= ln) ? t[e] : -1e30f;
        } else {
          sv[j] = t;
        }
      }
    }
    __builtin_amdgcn_s_setprio(0);

    // online softmax (exp2 domain), per q-row = per ln; max as tree
    float tj[8];
    #pragma unroll
    for (int j = 0; j < 8; ++j)
      tj[j] = fmaxf(fmaxf(sv[j][0], sv[j][1]), fmaxf(sv[j][2], sv[j][3]));
    float tm = fmaxf(fmaxf(fmaxf(tj[0], tj[1]), fmaxf(tj[2], tj[3])),
                     fmaxf(fmaxf(tj[4], tj[5]), fmaxf(tj[6], tj[7])));
    tm = fmaxf(tm, __shfl_xor(tm, 16));
    tm = fmaxf(tm, __shfl_xor(tm, 32));
    const float nm = fmaxf(m_run, tm);
    const float al = exp2f(m_run - nm);
    m_run = nm;

    // P = exp2(S - nm), packed to bf16 pairs per j
    unsigned pk[8][2];
    float rs = 0.f;
    #pragma unroll
    for (int j = 0; j < 8; ++j) {
      const float p0 = exp2f(sv[j][0] - nm), p1 = exp2f(sv[j][1] - nm);
      const float p2 = exp2f(sv[j][2] - nm), p3 = exp2f(sv[j][3] - nm);
      rs += (p0 + p1) + (p2 + p3);
      pk[j][0] = pkbf(p0, p1);
      pk[j][1] = pkbf(p2, p3);
    }
    rs += __shfl_xor(rs, 16);
    rs += __shfl_xor(rs, 32);
    l_run = l_run * al + rs;
    #pragma unroll
    for (int dj = 0; dj < 4; ++dj) acc[dj] *= al;

    // build PV B-fragments per 32-key slice ks:
    // lane (g,ln) needs P[q=ln][k = ks*32 + 8g..8g+7]
    const int ksmax = (jmax >> 1) + 1;
    short8 pf[4];
    #pragma unroll
    for (int ks = 0; ks < 4; ++ks) {
      if (ks < ksmax) {
        unsigned a0 = __shfl(pk[2 * ks][0], srcA);
        unsigned a1 = __shfl(pk[2 * ks][1], srcA);
        unsigned a2 = __shfl(pk[2 * ks][0], srcB);
        unsigned a3 = __shfl(pk[2 * ks][1], srcB);
        unsigned b0 = __shfl(pk[2 * ks + 1][0], srcA);
        unsigned b1 = __shfl(pk[2 * ks + 1][1], srcA);
        unsigned b2 = __shfl(pk[2 * ks + 1][0], srcB);
        unsigned b3 = __shfl(pk[2 * ks + 1][1], srcB);
        uintx4 u;
        u[0] = hi ? b0 : a0; u[1] = hi ? b1 : a1;
        u[2] = hi ? b2 : a2; u[3] = hi ? b3 : a3;
        pf[ks] = __builtin_bit_cast(short8, u);
      }
    }

    // PV swapped: acc rows = d (4g+e), cols = q (ln).
    // V LDS row = d (64 rows x 128 cols), colgroup swizzle ^= row&15 (=ln)
    __builtin_amdgcn_s_setprio(1);
    #pragma unroll
    for (int dj = 0; dj < 4; ++dj) {
      #pragma unroll
      for (int ks = 0; ks < 4; ++ks) {
        if (ks < ksmax) {
          short8 vb = *(const short8*)(
              &Vl[cur][(dj * 16 + ln) * 128 + (((ks * 4 + g) ^ ln) * 8)]);
          acc[dj] = mfma16(vb, pf[ks], acc[dj]);
        }
      }
    }
    __builtin_amdgcn_s_setprio(0);

    asm volatile("" ::: "memory");
    __builtin_amdgcn_s_barrier();
  }

  // epilogue: O[q = qw+ln][d = dj*16 + 4g+e], thread-local 1/l
  const float inv = 1.f / l_run;
  const size_t orow = ((size_t)b * SEQ + qw + ln) * EMB + h * HD;
  #pragma unroll
  for (int dj = 0; dj < 4; ++dj) {
    ushortx4 o;
    #pragma unroll
    for (int e = 0; e < 4; ++e) o[e] = bf16u(acc[dj][e] * inv);
    *(ushortx4*)(O + orow + dj * 16 + 4 * g) = o;
  }
}

// ---------------------------------------------------------------------------
// Output projection: fp32 out = AttnOut(bf16) @ Wo + bo.
// Operand-swapped so regs walk n -> float4 stores.  2-phase prefetch as qkv.
// ---------------------------------------------------------------------------
__global__ __launch_bounds__(256) void gemm_o_kernel(
    const unsigned short* __restrict__ Ab, const unsigned short* __restrict__ Wt,
    const float* __restrict__ bias, float* __restrict__ out) {
  __shared__ __align__(16) unsigned short AsB[2][128 * 64];
  __shared__ __align__(16) unsigned short BsB[2][128 * 64];
  const int m0 = blockIdx.y * 128, n0 = blockIdx.x * 128;
  const int tid = threadIdx.x, l = tid & 63, w = tid >> 6;
  const int g = l >> 4, ln = l & 15;
  const int wr = w >> 1, wc = w & 1;

  f32x4 acc[4][4];
  #pragma unroll
  for (int i = 0; i < 4; ++i)
    #pragma unroll
    for (int j = 0; j < 4; ++j) acc[i][j] = (f32x4){0.f, 0.f, 0.f, 0.f};

  GEMM_STAGE(Ab, Wt, 0, 0);
  #pragma unroll 1
  for (int kt = 0; kt < 16; ++kt) {
    const int cur = kt & 1;
    if (kt + 1 < 16) {
      GEMM_STAGE(Ab, Wt, kt + 1, cur ^ 1);
      asm volatile("s_waitcnt vmcnt(8)" ::: "memory");
    } else {
      asm volatile("s_waitcnt vmcnt(0)" ::: "memory");
    }
    __builtin_amdgcn_s_barrier();
    const unsigned short* As = &AsB[cur][0];
    const unsigned short* Bs = &BsB[cur][0];
    GEMM_KLOOP(b[j], a[i])
    asm volatile("" ::: "memory");
    __builtin_amdgcn_s_barrier();
  }

  const int mb = m0 + wr * 64, nb = n0 + wc * 64;
  #pragma unroll
  for (int j = 0; j < 4; ++j) {
    const int n = nb + j * 16 + 4 * g;
    floatx4 bv_ = *(const floatx4*)(bias + n);
    #pragma unroll
    for (int i = 0; i < 4; ++i) {
      const int m = mb + i * 16 + ln;
      floatx4 o = acc[i][j] + bv_;
      *(floatx4*)(out + (size_t)m * EMB + n) = o;
    }
  }
}

// ---------------------------------------------------------------------------
extern "C" void kernel_launch(void* const* d_in, const int* in_sizes, int n_in,
                              void* d_out, int out_size, void* d_ws, size_t ws_size,
                              hipStream_t stream) {
  const float* x  = (const float*)d_in[0];
  const float* Wq = (const float*)d_in[1];
  const float* bq = (const float*)d_in[2];
  const float* Wk = (const float*)d_in[3];
  const float* bk = (const float*)d_in[4];
  const float* Wv = (const float*)d_in[5];
  const float* bv = (const float*)d_in[6];
  const float* Wo = (const float*)d_in[7];
  const float* bo = (const float*)d_in[8];
  float* out = (float*)d_out;

  char* ws = (char*)d_ws;
  unsigned short* Xb  = (unsigned short*)(ws);              // 8 MB  [4096][1024]
  unsigned short* WqT = (unsigned short*)(ws + 8388608);    // 2 MB each [n][k]
  unsigned short* WkT = (unsigned short*)(ws + 10485760);
  unsigned short* WvT = (unsigned short*)(ws + 12582912);
  unsigned short* WoT = (unsigned short*)(ws + 14680064);
  unsigned short* Qb  = (unsigned short*)(ws + 16777216);   // 8 MB [b][h][s][d]
  unsigned short* Kb  = (unsigned short*)(ws + 25165824);   // 8 MB [b][h][s][d]
  unsigned short* Vtb = (unsigned short*)(ws + 33554432);   // 8 MB [b][h][d][s]
  unsigned short* Ao  = Xb;  // attention output reuses Xb (stream-ordered)

  hipLaunchKernelGGL(cvt_all_kernel, dim3(32, 32, 5), dim3(256), 0, stream,
                     x, Xb, Wq, Wk, Wv, Wo, WqT, WkT, WvT, WoT);
  hipLaunchKernelGGL(gemm_qkv_kernel, dim3(8, 32, 3), dim3(256), 0, stream,
                     Xb, WqT, WkT, WvT, bq, bk, bv, Qb, Kb, Vtb);
  hipLaunchKernelGGL(attn_kernel, dim3(512), dim3(512), 0, stream,
                     Qb, Kb, Vtb, Ao);
  hipLaunchKernelGGL(gemm_o_kernel, dim3(8, 32), dim3(256), 0, stream,
                     Ao, WoT, bo, out);
}

// Round 16
// 154.464 us; speedup vs baseline: 1.0575x; 1.0267x over previous
//
#include <hip/hip_runtime.h>

// ---------------------------------------------------------------------------
// Causal MHA block: QKV proj (bf16 MFMA) -> flash attention -> out proj.
// B=2, S=2048, E=1024, H=16, D=64.
// r16 = r15 with gemm_o retiled 128x128 -> 64x128 (grid 512, 2-3 blocks/CU
// co-resident vs 1 before).  Everything else byte-identical to r15.
// ---------------------------------------------------------------------------

#define EMB 1024
#define SEQ 2048
#define NB 2
#define NH 16
#define HD 64

// 0.125 (1/sqrt(64)) * log2(e): QK logits land in exp2 domain
#define QSCALE 0.18033688011112042f

typedef float f32x4 __attribute__((ext_vector_type(4)));
typedef float floatx4 __attribute__((ext_vector_type(4)));
typedef short short8 __attribute__((ext_vector_type(8)));
typedef __bf16 bf16x8 __attribute__((ext_vector_type(8)));
typedef __bf16 bf16x2 __attribute__((ext_vector_type(2)));
typedef unsigned short ushortx4 __attribute__((ext_vector_type(4)));
typedef unsigned int uintx4 __attribute__((ext_vector_type(4)));

// native f32->bf16 (RNE, compiler emits v_cvt_pk_bf16_f32 for pairs)
__device__ __forceinline__ unsigned short bf16u(float f) {
  __bf16 h = (__bf16)f;
  return __builtin_bit_cast(unsigned short, h);
}

__device__ __forceinline__ unsigned pkbf(float lo, float hi) {
  bf16x2 v;
  v[0] = (__bf16)lo;
  v[1] = (__bf16)hi;
  return __builtin_bit_cast(unsigned, v);
}

__device__ __forceinline__ f32x4 mfma16(short8 a, short8 b, f32x4 c) {
  return __builtin_amdgcn_mfma_f32_16x16x32_bf16(
      __builtin_bit_cast(bf16x8, a), __builtin_bit_cast(bf16x8, b), c, 0, 0, 0);
}

// async global -> LDS, 16B per lane; lds dest is wave-uniform base + lane*16
__device__ __forceinline__ void gload16(const void* g, void* lds) {
  __builtin_amdgcn_global_load_lds(
      (const __attribute__((address_space(1))) unsigned int*)g,
      (__attribute__((address_space(3))) unsigned int*)lds, 16, 0, 0);
}

// ---------------------------------------------------------------------------
// Merged converts: z<4 -> fp32 W[k][n] -> bf16 WT[n][k] (32x32 LDS transpose);
// z==4 -> fp32 x -> bf16 (16 elements/thread, float4-coalesced).
// ---------------------------------------------------------------------------
__global__ __launch_bounds__(256) void cvt_all_kernel(
    const float* __restrict__ x, unsigned short* __restrict__ Xb,
    const float* __restrict__ W0, const float* __restrict__ W1,
    const float* __restrict__ W2, const float* __restrict__ W3,
    unsigned short* __restrict__ T0, unsigned short* __restrict__ T1,
    unsigned short* __restrict__ T2, unsigned short* __restrict__ T3) {
  const int z = blockIdx.z;
  const int t = threadIdx.x;
  if (z == 4) {
    // x convert: 1024 virtual blocks of 4096 elements
    const int blin = blockIdx.y * 32 + blockIdx.x;
    const int base = blin * 4096 + t * 4;
    #pragma unroll
    for (int c = 0; c < 4; ++c) {
      const int idx = base + c * 1024;
      floatx4 v = *(const floatx4*)(x + idx);
      ushortx4 o;
      #pragma unroll
      for (int i = 0; i < 4; ++i) o[i] = bf16u(v[i]);
      *(ushortx4*)(Xb + idx) = o;
    }
    return;
  }
  __shared__ unsigned short tile[32][33];
  const float* W = (z == 0) ? W0 : (z == 1) ? W1 : (z == 2) ? W2 : W3;
  unsigned short* WT = (z == 0) ? T0 : (z == 1) ? T1 : (z == 2) ? T2 : T3;
  const int k0 = blockIdx.x * 32, n0 = blockIdx.y * 32;
  const int r = t >> 3, c = (t & 7) * 4;
  floatx4 v = *(const floatx4*)(W + (k0 + r) * EMB + n0 + c);
  #pragma unroll
  for (int i = 0; i < 4; ++i) tile[r][c + i] = bf16u(v[i]);
  __syncthreads();
  ushortx4 o;
  #pragma unroll
  for (int i = 0; i < 4; ++i) o[i] = tile[c + i][r];
  *(ushortx4*)(WT + (n0 + r) * EMB + k0 + c) = o;
}

// shared k-loop body for the 128x128 GEMMs; OP1's tile index lands on the
// accumulator reg axis (4g+e), OP2's on the lane-col axis (ln).
#define GEMM_KLOOP(OP1, OP2)                                                 \
    for (int kk = 0; kk < 64; kk += 32) {                                    \
      short8 a[4], b[4];                                                     \
      _Pragma("unroll")                                                      \
      for (int i = 0; i < 4; ++i)                                            \
        a[i] = *(const short8*)(As + (wr * 64 + i * 16 + ln) * 64 + kk + g * 8); \
      _Pragma("unroll")                                                      \
      for (int j = 0; j < 4; ++j)                                            \
        b[j] = *(const short8*)(Bs + (wc * 64 + j * 16 + ln) * 64 + kk + g * 8); \
      _Pragma("unroll")                                                      \
      for (int i = 0; i < 4; ++i)                                            \
        _Pragma("unroll")                                                    \
        for (int j = 0; j < 4; ++j)                                          \
          acc[i][j] = mfma16(OP1, OP2, acc[i][j]);                           \
    }

#define GEMM_STAGE(Aptr, Bptr, kt_, buf_)                                    \
    do {                                                                     \
      const int kb_ = (kt_) * 64;                                            \
      _Pragma("unroll")                                                      \
      for (int it = 0; it < 4; ++it) {                                       \
        const int chunk = w * 4 + it;                                        \
        const int lin = chunk * 64 + l;                                      \
        const int row = lin >> 3, col = (lin & 7) * 8;                       \
        gload16(Aptr + (m0 + row) * EMB + kb_ + col,                         \
                (char*)&AsB[buf_][0] + chunk * 1024);                        \
        gload16(Bptr + (n0 + row) * EMB + kb_ + col,                         \
                (char*)&BsB[buf_][0] + chunk * 1024);                        \
      }                                                                      \
    } while (0)

// ---------------------------------------------------------------------------
// GEMM: C[m][n] = Xb[m][k] * WT[n][k]^T + bias.  128x128 tile, BK=64, 4 waves,
// 2-phase double-buffered staging (counted vmcnt(8), never 0 mid-loop).
// z=0 -> Q[b][h][s][d] (pre-scaled by QSCALE), z=1 -> K[b][h][s][d]:
//   operand-swapped MFMA so regs walk d -> packed ushortx4 stores.
// z=2 -> Vt[b][h][d][s]: normal order so regs walk s -> packed stores.
// ---------------------------------------------------------------------------
__global__ __launch_bounds__(256) void gemm_qkv_kernel(
    const unsigned short* __restrict__ Xb,
    const unsigned short* __restrict__ W0, const unsigned short* __restrict__ W1,
    const unsigned short* __restrict__ W2,
    const float* __restrict__ b0, const float* __restrict__ b1,
    const float* __restrict__ b2,
    unsigned short* __restrict__ Qo, unsigned short* __restrict__ Ko,
    unsigned short* __restrict__ Vo) {
  __shared__ __align__(16) unsigned short AsB[2][128 * 64];
  __shared__ __align__(16) unsigned short BsB[2][128 * 64];
  const int z = blockIdx.z;
  const unsigned short* Wt = (z == 0) ? W0 : ((z == 1) ? W1 : W2);
  const float* bias = (z == 0) ? b0 : ((z == 1) ? b1 : b2);
  const bool sw = (z != 2);
  const int m0 = blockIdx.y * 128, n0 = blockIdx.x * 128;
  const int tid = threadIdx.x, l = tid & 63, w = tid >> 6;
  const int g = l >> 4, ln = l & 15;
  const int wr = w >> 1, wc = w & 1;

  f32x4 acc[4][4];
  #pragma unroll
  for (int i = 0; i < 4; ++i)
    #pragma unroll
    for (int j = 0; j < 4; ++j) acc[i][j] = (f32x4){0.f, 0.f, 0.f, 0.f};

  GEMM_STAGE(Xb, Wt, 0, 0);
  #pragma unroll 1
  for (int kt = 0; kt < 16; ++kt) {
    const int cur = kt & 1;
    if (kt + 1 < 16) {
      GEMM_STAGE(Xb, Wt, kt + 1, cur ^ 1);
      asm volatile("s_waitcnt vmcnt(8)" ::: "memory");
    } else {
      asm volatile("s_waitcnt vmcnt(0)" ::: "memory");
    }
    __builtin_amdgcn_s_barrier();
    const unsigned short* As = &AsB[cur][0];
    const unsigned short* Bs = &BsB[cur][0];
    if (sw) {
      GEMM_KLOOP(b[j], a[i])
    } else {
      GEMM_KLOOP(a[i], b[j])
    }
    asm volatile("" ::: "memory");
    __builtin_amdgcn_s_barrier();
  }

  const int mb = m0 + wr * 64, nb = n0 + wc * 64;
  if (sw) {
    unsigned short* dst = (z == 0) ? Qo : Ko;
    const float osc = (z == 0) ? QSCALE : 1.0f;
    #pragma unroll
    for (int j = 0; j < 4; ++j) {
      const int n = nb + j * 16 + 4 * g;
      floatx4 bv_ = *(const floatx4*)(bias + n);
      const int h = n >> 6, d = n & 63;
      #pragma unroll
      for (int i = 0; i < 4; ++i) {
        const int m = mb + i * 16 + ln;
        const int bb = m >> 11, ss = m & 2047;
        ushortx4 o;
        #pragma unroll
        for (int e = 0; e < 4; ++e) o[e] = bf16u((acc[i][j][e] + bv_[e]) * osc);
        *(ushortx4*)(dst + ((bb * NH + h) * SEQ + ss) * HD + d) = o;
      }
    }
  } else {
    #pragma unroll
    for (int j = 0; j < 4; ++j) {
      const int n = nb + j * 16 + ln;
      const float bgain = bias[n];
      const int h = n >> 6, d = n & 63;
      #pragma unroll
      for (int i = 0; i < 4; ++i) {
        const int mf = mb + i * 16 + 4 * g;
        const int bb = mf >> 11, ss = mf & 2047;
        ushortx4 o;
        #pragma unroll
        for (int e = 0; e < 4; ++e) o[e] = bf16u(acc[i][j][e] + bgain);
        *(ushortx4*)(Vo + ((bb * NH + h) * HD + d) * SEQ + ss) = o;
      }
    }
  }
}

// ---------------------------------------------------------------------------
// Causal flash attention (r9 known-good: 66.5 us).  Unchanged from r15.
// ---------------------------------------------------------------------------
__global__ __launch_bounds__(512) void attn_kernel(
    const unsigned short* __restrict__ Q, const unsigned short* __restrict__ K,
    const unsigned short* __restrict__ Vt, unsigned short* __restrict__ O) {
  __shared__ __align__(16) unsigned short Kt[2][128 * 64];
  __shared__ __align__(16) unsigned short Vl[2][64 * 128];
  const int id = blockIdx.x;
  const int bh = id & 31;
  const int grp = id >> 5;
  const int T = (grp < 8) ? (15 - grp) : (grp - 8);
  const int h = bh & 15, b = bh >> 4;
  const int tid = threadIdx.x, l = tid & 63, w = tid >> 6;   // w = 0..7
  const int g = l >> 4, ln = l & 15;
  const size_t baseQK = (size_t)bh * SEQ * HD;   // [s][d]
  const size_t baseV = (size_t)bh * HD * SEQ;    // [d][s]
  const int xr = ln & 7;                          // K read-side swizzle xor
  const int srcA = ((g & 1) << 5) + ln;           // P-shuffle source lanes
  const int srcB = srcA + 16;
  const bool hi = (g >> 1) != 0;

  // K staging: chunks 2w,2w+1 of 16 (1KB = 8 rows x 128B)
  const int kr0 = (2 * w) * 8 + (l >> 3), kr1 = (2 * w + 1) * 8 + (l >> 3);
  const int kc0 = (l & 7) ^ (kr0 & 7), kc1 = (l & 7) ^ (kr1 & 7);
  // V staging: chunks 2w,2w+1 of 16 (1KB = 4 rows x 256B)
  const int vr0 = (2 * w) * 4 + (l >> 4), vr1 = (2 * w + 1) * 4 + (l >> 4);
  const int vc0 = (l & 15) ^ (vr0 & 15), vc1 = (l & 15) ^ (vr1 & 15);

  const int nkt = T + 1;
  const int qw = T * 128 + w * 16;

  // stage kt=0 into buf 0 (4 gload_lds per wave)
  gload16(K + baseQK + (size_t)kr0 * HD + kc0 * 8,
          (char*)&Kt[0][0] + (2 * w) * 1024);
  gload16(K + baseQK + (size_t)kr1 * HD + kc1 * 8,
          (char*)&Kt[0][0] + (2 * w + 1) * 1024);
  gload16(Vt + baseV + (size_t)vr0 * SEQ + vc0 * 8,
          (char*)&Vl[0][0] + (2 * w) * 1024);
  gload16(Vt + baseV + (size_t)vr1 * SEQ + vc1 * 8,
          (char*)&Vl[0][0] + (2 * w + 1) * 1024);

  // Q fragments (B-operand: col = q = ln, contraction d)
  const int qrow = qw + ln;
  short8 qf0 = *(const short8*)(Q + baseQK + (size_t)qrow * HD + g * 8);
  short8 qf1 = *(const short8*)(Q + baseQK + (size_t)qrow * HD + 32 + g * 8);

  float m_run = -1e30f, l_run = 0.f;
  f32x4 acc[4];
  #pragma unroll
  for (int dj = 0; dj < 4; ++dj) acc[dj] = (f32x4){0.f, 0.f, 0.f, 0.f};

  #pragma unroll 1
  for (int kt = 0; kt < nkt; ++kt) {
    const int cur = kt & 1;
    const bool has_next = (kt + 1 < nkt);
    if (has_next) {  // prefetch next 128-key tile into other buffer
      const int nxt = cur ^ 1;
      const size_t kof = (size_t)(kt + 1) * 128;
      gload16(K + baseQK + (kof + kr0) * HD + kc0 * 8,
              (char*)&Kt[nxt][0] + (2 * w) * 1024);
      gload16(K + baseQK + (kof + kr1) * HD + kc1 * 8,
              (char*)&Kt[nxt][0] + (2 * w + 1) * 1024);
      gload16(Vt + baseV + (size_t)vr0 * SEQ + kof + vc0 * 8,
              (char*)&Vl[nxt][0] + (2 * w) * 1024);
      gload16(Vt + baseV + (size_t)vr1 * SEQ + kof + vc1 * 8,
              (char*)&Vl[nxt][0] + (2 * w + 1) * 1024);
      asm volatile("s_waitcnt vmcnt(4)" ::: "memory");
    } else {
      asm volatile("s_waitcnt vmcnt(0)" ::: "memory");
    }
    __builtin_amdgcn_s_barrier();

    const bool last = (kt == T);
    const int jmax = last ? w : 7;

    // QK^T swapped: sv[j][e] = S[q=qw+ln][k = kt*128 + j*16 + 4g+e]
    f32x4 sv[8];
    #pragma unroll
    for (int j = 0; j < 8; ++j)
      sv[j] = (f32x4){-1e30f, -1e30f, -1e30f, -1e30f};
    __builtin_amdgcn_s_setprio(1);
    #pragma unroll
    for (int j = 0; j < 8; ++j) {
      if (j <= jmax) {
        f32x4 t = (f32x4){0.f, 0.f, 0.f, 0.f};
        short8 kf0 = *(const short8*)(
            &Kt[cur][(j * 16 + ln) * 64 + ((g ^ xr) * 8)]);
        t = mfma16(kf0, qf0, t);
        short8 kf1 = *(const short8*)(
            &Kt[cur][(j * 16 + ln) * 64 + (((4 + g) ^ xr) * 8)]);
        t = mfma16(kf1, qf1, t);
        if (last && j == w) {               // triangle tile
          #pragma unroll
          for (int e = 0; e < 4; ++e)
            sv[j][e] = (4 * g + e <= ln) ? t[e] : -1e30f;
        } else {
          sv[j] = t;
        }
      }
    }
    __builtin_amdgcn_s_setprio(0);

    // online softmax (exp2 domain), per q-row = per ln; max as tree
    float tj[8];
    #pragma unroll
    for (int j = 0; j < 8; ++j)
      tj[j] = fmaxf(fmaxf(sv[j][0], sv[j][1]), fmaxf(sv[j][2], sv[j][3]));
    float tm = fmaxf(fmaxf(fmaxf(tj[0], tj[1]), fmaxf(tj[2], tj[3])),
                     fmaxf(fmaxf(tj[4], tj[5]), fmaxf(tj[6], tj[7])));
    tm = fmaxf(tm, __shfl_xor(tm, 16));
    tm = fmaxf(tm, __shfl_xor(tm, 32));
    const float nm = fmaxf(m_run, tm);
    const float al = exp2f(m_run - nm);
    m_run = nm;

    // P = exp2(S - nm), packed to bf16 pairs per j
    unsigned pk[8][2];
    float rs = 0.f;
    #pragma unroll
    for (int j = 0; j < 8; ++j) {
      const float p0 = exp2f(sv[j][0] - nm), p1 = exp2f(sv[j][1] - nm);
      const float p2 = exp2f(sv[j][2] - nm), p3 = exp2f(sv[j][3] - nm);
      rs += (p0 + p1) + (p2 + p3);
      pk[j][0] = pkbf(p0, p1);
      pk[j][1] = pkbf(p2, p3);
    }
    rs += __shfl_xor(rs, 16);
    rs += __shfl_xor(rs, 32);
    l_run = l_run * al + rs;
    #pragma unroll
    for (int dj = 0; dj < 4; ++dj) acc[dj] *= al;

    // build PV B-fragments per 32-key slice ks:
    // lane (g,ln) needs P[q=ln][k = ks*32 + 8g..8g+7]
    const int ksmax = (jmax >> 1) + 1;
    short8 pf[4];
    #pragma unroll
    for (int ks = 0; ks < 4; ++ks) {
      if (ks < ksmax) {
        unsigned a0 = __shfl(pk[2 * ks][0], srcA);
        unsigned a1 = __shfl(pk[2 * ks][1], srcA);
        unsigned a2 = __shfl(pk[2 * ks][0], srcB);
        unsigned a3 = __shfl(pk[2 * ks][1], srcB);
        unsigned b0 = __shfl(pk[2 * ks + 1][0], srcA);
        unsigned b1 = __shfl(pk[2 * ks + 1][1], srcA);
        unsigned b2 = __shfl(pk[2 * ks + 1][0], srcB);
        unsigned b3 = __shfl(pk[2 * ks + 1][1], srcB);
        uintx4 u;
        u[0] = hi ? b0 : a0; u[1] = hi ? b1 : a1;
        u[2] = hi ? b2 : a2; u[3] = hi ? b3 : a3;
        pf[ks] = __builtin_bit_cast(short8, u);
      }
    }

    // PV swapped: acc rows = d (4g+e), cols = q (ln).
    // V LDS row = d (64 rows x 128 cols), colgroup swizzle ^= row&15 (=ln)
    __builtin_amdgcn_s_setprio(1);
    #pragma unroll
    for (int dj = 0; dj < 4; ++dj) {
      #pragma unroll
      for (int ks = 0; ks < 4; ++ks) {
        if (ks < ksmax) {
          short8 vb = *(const short8*)(
              &Vl[cur][(dj * 16 + ln) * 128 + (((ks * 4 + g) ^ ln) * 8)]);
          acc[dj] = mfma16(vb, pf[ks], acc[dj]);
        }
      }
    }
    __builtin_amdgcn_s_setprio(0);

    asm volatile("" ::: "memory");
    __builtin_amdgcn_s_barrier();
  }

  // epilogue: O[q = qw+ln][d = dj*16 + 4g+e], thread-local 1/l
  const float inv = 1.f / l_run;
  const size_t orow = ((size_t)b * SEQ + qw + ln) * EMB + h * HD;
  #pragma unroll
  for (int dj = 0; dj < 4; ++dj) {
    ushortx4 o;
    #pragma unroll
    for (int e = 0; e < 4; ++e) o[e] = bf16u(acc[dj][e] * inv);
    *(ushortx4*)(O + orow + dj * 16 + 4 * g) = o;
  }
}

// ---------------------------------------------------------------------------
// Output projection: fp32 out = AttnOut(bf16) @ Wo + bo.
// r16: 64x128 tile (BM=64), 4 waves each owning 64x32 (wave index on N).
// Operand-swapped so regs walk n -> float4 stores.  2-phase, vmcnt(6).
// Grid (8, 64) = 512 blocks -> 2-3 co-resident blocks/CU (LDS 48KB).
// ---------------------------------------------------------------------------
__global__ __launch_bounds__(256) void gemm_o_kernel(
    const unsigned short* __restrict__ Ab, const unsigned short* __restrict__ Wt,
    const float* __restrict__ bias, float* __restrict__ out) {
  __shared__ __align__(16) unsigned short AsB[2][64 * 64];
  __shared__ __align__(16) unsigned short BsB[2][128 * 64];
  const int m0 = blockIdx.y * 64, n0 = blockIdx.x * 128;
  const int tid = threadIdx.x, l = tid & 63, w = tid >> 6;
  const int g = l >> 4, ln = l & 15;

  f32x4 acc[4][2];
  #pragma unroll
  for (int i = 0; i < 4; ++i)
    #pragma unroll
    for (int j = 0; j < 2; ++j) acc[i][j] = (f32x4){0.f, 0.f, 0.f, 0.f};

  // stage: A 8 chunks (wave w: 2w,2w+1), B 16 chunks (wave w: 4w..4w+3)
  #define GEMM_STAGE64(kt_, buf_)                                            \
      do {                                                                   \
        const int kb_ = (kt_) * 64;                                          \
        _Pragma("unroll")                                                    \
        for (int it = 0; it < 2; ++it) {                                     \
          const int chunk = w * 2 + it;                                      \
          const int lin = chunk * 64 + l;                                    \
          const int row = lin >> 3, col = (l & 7) * 8;                       \
          gload16(Ab + (m0 + row) * EMB + kb_ + col,                         \
                  (char*)&AsB[buf_][0] + chunk * 1024);                      \
        }                                                                    \
        _Pragma("unroll")                                                    \
        for (int it = 0; it < 4; ++it) {                                     \
          const int chunk = w * 4 + it;                                      \
          const int lin = chunk * 64 + l;                                    \
          const int row = lin >> 3, col = (l & 7) * 8;                       \
          gload16(Wt + (n0 + row) * EMB + kb_ + col,                         \
                  (char*)&BsB[buf_][0] + chunk * 1024);                      \
        }                                                                    \
      } while (0)

  GEMM_STAGE64(0, 0);
  #pragma unroll 1
  for (int kt = 0; kt < 16; ++kt) {
    const int cur = kt & 1;
    if (kt + 1 < 16) {
      GEMM_STAGE64(kt + 1, cur ^ 1);
      asm volatile("s_waitcnt vmcnt(6)" ::: "memory");
    } else {
      asm volatile("s_waitcnt vmcnt(0)" ::: "memory");
    }
    __builtin_amdgcn_s_barrier();
    const unsigned short* As = &AsB[cur][0];
    const unsigned short* Bs = &BsB[cur][0];
    #pragma unroll
    for (int kk = 0; kk < 64; kk += 32) {
      short8 a[4], b[2];
      #pragma unroll
      for (int i = 0; i < 4; ++i)
        a[i] = *(const short8*)(As + (i * 16 + ln) * 64 + kk + g * 8);
      #pragma unroll
      for (int j = 0; j < 2; ++j)
        b[j] = *(const short8*)(Bs + (w * 32 + j * 16 + ln) * 64 + kk + g * 8);
      #pragma unroll
      for (int i = 0; i < 4; ++i)
        #pragma unroll
        for (int j = 0; j < 2; ++j)
          acc[i][j] = mfma16(b[j], a[i], acc[i][j]);
    }
    asm volatile("" ::: "memory");
    __builtin_amdgcn_s_barrier();
  }
  #undef GEMM_STAGE64

  // epilogue: regs walk n; n = n0 + w*32 + j*16 + 4g, m = m0 + i*16 + ln
  #pragma unroll
  for (int j = 0; j < 2; ++j) {
    const int n = n0 + w * 32 + j * 16 + 4 * g;
    floatx4 bv_ = *(const floatx4*)(bias + n);
    #pragma unroll
    for (int i = 0; i < 4; ++i) {
      const int m = m0 + i * 16 + ln;
      floatx4 o = acc[i][j] + bv_;
      *(floatx4*)(out + (size_t)m * EMB + n) = o;
    }
  }
}

// ---------------------------------------------------------------------------
extern "C" void kernel_launch(void* const* d_in, const int* in_sizes, int n_in,
                              void* d_out, int out_size, void* d_ws, size_t ws_size,
                              hipStream_t stream) {
  const float* x  = (const float*)d_in[0];
  const float* Wq = (const float*)d_in[1];
  const float* bq = (const float*)d_in[2];
  const float* Wk = (const float*)d_in[3];
  const float* bk = (const float*)d_in[4];
  const float* Wv = (const float*)d_in[5];
  const float* bv = (const float*)d_in[6];
  const float* Wo = (const float*)d_in[7];
  const float* bo = (const float*)d_in[8];
  float* out = (float*)d_out;

  char* ws = (char*)d_ws;
  unsigned short* Xb  = (unsigned short*)(ws);              // 8 MB  [4096][1024]
  unsigned short* WqT = (unsigned short*)(ws + 8388608);    // 2 MB each [n][k]
  unsigned short* WkT = (unsigned short*)(ws + 10485760);
  unsigned short* WvT = (unsigned short*)(ws + 12582912);
  unsigned short* WoT = (unsigned short*)(ws + 14680064);
  unsigned short* Qb  = (unsigned short*)(ws + 16777216);   // 8 MB [b][h][s][d]
  unsigned short* Kb  = (unsigned short*)(ws + 25165824);   // 8 MB [b][h][s][d]
  unsigned short* Vtb = (unsigned short*)(ws + 33554432);   // 8 MB [b][h][d][s]
  unsigned short* Ao  = Xb;  // attention output reuses Xb (stream-ordered)

  hipLaunchKernelGGL(cvt_all_kernel, dim3(32, 32, 5), dim3(256), 0, stream,
                     x, Xb, Wq, Wk, Wv, Wo, WqT, WkT, WvT, WoT);
  hipLaunchKernelGGL(gemm_qkv_kernel, dim3(8, 32, 3), dim3(256), 0, stream,
                     Xb, WqT, WkT, WvT, bq, bk, bv, Qb, Kb, Vtb);
  hipLaunchKernelGGL(attn_kernel, dim3(512), dim3(512), 0, stream,
                     Qb, Kb, Vtb, Ao);
  hipLaunchKernelGGL(gemm_o_kernel, dim3(8, 64), dim3(256), 0, stream,
                     Ao, WoT, bo, out);
}

// Round 17
// 145.719 us; speedup vs baseline: 1.1210x; 1.0600x over previous
//
#include <hip/hip_runtime.h>

// ---------------------------------------------------------------------------
// Causal MHA block: QKV proj (bf16 MFMA) -> flash attention -> out proj.
// B=2, S=2048, E=1024, H=16, D=64.
// r17 = r16 with gemm_qkv also retiled 128x128 -> 64x128 (grid (8,64,3) =
// 1536 blocks, 48KB LDS -> 3 co-resident blocks/CU).  Everything else
// byte-identical to r16.
// ---------------------------------------------------------------------------

#define EMB 1024
#define SEQ 2048
#define NB 2
#define NH 16
#define HD 64

// 0.125 (1/sqrt(64)) * log2(e): QK logits land in exp2 domain
#define QSCALE 0.18033688011112042f

typedef float f32x4 __attribute__((ext_vector_type(4)));
typedef float floatx4 __attribute__((ext_vector_type(4)));
typedef short short8 __attribute__((ext_vector_type(8)));
typedef __bf16 bf16x8 __attribute__((ext_vector_type(8)));
typedef __bf16 bf16x2 __attribute__((ext_vector_type(2)));
typedef unsigned short ushortx4 __attribute__((ext_vector_type(4)));
typedef unsigned int uintx4 __attribute__((ext_vector_type(4)));

// native f32->bf16 (RNE, compiler emits v_cvt_pk_bf16_f32 for pairs)
__device__ __forceinline__ unsigned short bf16u(float f) {
  __bf16 h = (__bf16)f;
  return __builtin_bit_cast(unsigned short, h);
}

__device__ __forceinline__ unsigned pkbf(float lo, float hi) {
  bf16x2 v;
  v[0] = (__bf16)lo;
  v[1] = (__bf16)hi;
  return __builtin_bit_cast(unsigned, v);
}

__device__ __forceinline__ f32x4 mfma16(short8 a, short8 b, f32x4 c) {
  return __builtin_amdgcn_mfma_f32_16x16x32_bf16(
      __builtin_bit_cast(bf16x8, a), __builtin_bit_cast(bf16x8, b), c, 0, 0, 0);
}

// async global -> LDS, 16B per lane; lds dest is wave-uniform base + lane*16
__device__ __forceinline__ void gload16(const void* g, void* lds) {
  __builtin_amdgcn_global_load_lds(
      (const __attribute__((address_space(1))) unsigned int*)g,
      (__attribute__((address_space(3))) unsigned int*)lds, 16, 0, 0);
}

// ---------------------------------------------------------------------------
// Merged converts: z<4 -> fp32 W[k][n] -> bf16 WT[n][k] (32x32 LDS transpose);
// z==4 -> fp32 x -> bf16 (16 elements/thread, float4-coalesced).
// ---------------------------------------------------------------------------
__global__ __launch_bounds__(256) void cvt_all_kernel(
    const float* __restrict__ x, unsigned short* __restrict__ Xb,
    const float* __restrict__ W0, const float* __restrict__ W1,
    const float* __restrict__ W2, const float* __restrict__ W3,
    unsigned short* __restrict__ T0, unsigned short* __restrict__ T1,
    unsigned short* __restrict__ T2, unsigned short* __restrict__ T3) {
  const int z = blockIdx.z;
  const int t = threadIdx.x;
  if (z == 4) {
    // x convert: 1024 virtual blocks of 4096 elements
    const int blin = blockIdx.y * 32 + blockIdx.x;
    const int base = blin * 4096 + t * 4;
    #pragma unroll
    for (int c = 0; c < 4; ++c) {
      const int idx = base + c * 1024;
      floatx4 v = *(const floatx4*)(x + idx);
      ushortx4 o;
      #pragma unroll
      for (int i = 0; i < 4; ++i) o[i] = bf16u(v[i]);
      *(ushortx4*)(Xb + idx) = o;
    }
    return;
  }
  __shared__ unsigned short tile[32][33];
  const float* W = (z == 0) ? W0 : (z == 1) ? W1 : (z == 2) ? W2 : W3;
  unsigned short* WT = (z == 0) ? T0 : (z == 1) ? T1 : (z == 2) ? T2 : T3;
  const int k0 = blockIdx.x * 32, n0 = blockIdx.y * 32;
  const int r = t >> 3, c = (t & 7) * 4;
  floatx4 v = *(const floatx4*)(W + (k0 + r) * EMB + n0 + c);
  #pragma unroll
  for (int i = 0; i < 4; ++i) tile[r][c + i] = bf16u(v[i]);
  __syncthreads();
  ushortx4 o;
  #pragma unroll
  for (int i = 0; i < 4; ++i) o[i] = tile[c + i][r];
  *(ushortx4*)(WT + (n0 + r) * EMB + k0 + c) = o;
}

// 64x128 staging: A 8 chunks (wave w: 2w,2w+1), B 16 chunks (wave w: 4w..4w+3)
#define GEMM_STAGE64(Aptr, Bptr, kt_, buf_)                                  \
    do {                                                                     \
      const int kb_ = (kt_) * 64;                                            \
      _Pragma("unroll")                                                      \
      for (int it = 0; it < 2; ++it) {                                       \
        const int chunk = w * 2 + it;                                        \
        const int lin = chunk * 64 + l;                                      \
        const int row = lin >> 3, col = (l & 7) * 8;                         \
        gload16(Aptr + (m0 + row) * EMB + kb_ + col,                         \
                (char*)&AsB[buf_][0] + chunk * 1024);                        \
      }                                                                      \
      _Pragma("unroll")                                                      \
      for (int it = 0; it < 4; ++it) {                                       \
        const int chunk = w * 4 + it;                                        \
        const int lin = chunk * 64 + l;                                      \
        const int row = lin >> 3, col = (l & 7) * 8;                         \
        gload16(Bptr + (n0 + row) * EMB + kb_ + col,                         \
                (char*)&BsB[buf_][0] + chunk * 1024);                        \
      }                                                                      \
    } while (0)

// 64x128 k-loop: a[4] over 64 m-rows, b[2] over wave's 32 n-cols at w*32
#define GEMM_KLOOP64(OP1, OP2)                                               \
    for (int kk = 0; kk < 64; kk += 32) {                                    \
      short8 a[4], b[2];                                                     \
      _Pragma("unroll")                                                      \
      for (int i = 0; i < 4; ++i)                                            \
        a[i] = *(const short8*)(As + (i * 16 + ln) * 64 + kk + g * 8);       \
      _Pragma("unroll")                                                      \
      for (int j = 0; j < 2; ++j)                                            \
        b[j] = *(const short8*)(Bs + (w * 32 + j * 16 + ln) * 64 + kk + g * 8); \
      _Pragma("unroll")                                                      \
      for (int i = 0; i < 4; ++i)                                            \
        _Pragma("unroll")                                                    \
        for (int j = 0; j < 2; ++j)                                          \
          acc[i][j] = mfma16(OP1, OP2, acc[i][j]);                           \
    }

// ---------------------------------------------------------------------------
// GEMM: C[m][n] = Xb[m][k] * WT[n][k]^T + bias.  64x128 tile, BK=64, 4 waves
// (wave index on N: per-wave 64x32 output), 2-phase dbuf, counted vmcnt(6).
// z=0 -> Q[b][h][s][d] (pre-scaled by QSCALE), z=1 -> K[b][h][s][d]:
//   operand-swapped MFMA so regs walk d -> packed ushortx4 stores.
// z=2 -> Vt[b][h][d][s]: normal order so regs walk s -> packed stores.
// Grid (8, 64, 3) = 1536 blocks, LDS 48KB -> 3 co-resident blocks/CU.
// ---------------------------------------------------------------------------
__global__ __launch_bounds__(256) void gemm_qkv_kernel(
    const unsigned short* __restrict__ Xb,
    const unsigned short* __restrict__ W0, const unsigned short* __restrict__ W1,
    const unsigned short* __restrict__ W2,
    const float* __restrict__ b0, const float* __restrict__ b1,
    const float* __restrict__ b2,
    unsigned short* __restrict__ Qo, unsigned short* __restrict__ Ko,
    unsigned short* __restrict__ Vo) {
  __shared__ __align__(16) unsigned short AsB[2][64 * 64];
  __shared__ __align__(16) unsigned short BsB[2][128 * 64];
  const int z = blockIdx.z;
  const unsigned short* Wt = (z == 0) ? W0 : ((z == 1) ? W1 : W2);
  const float* bias = (z == 0) ? b0 : ((z == 1) ? b1 : b2);
  const bool sw = (z != 2);
  const int m0 = blockIdx.y * 64, n0 = blockIdx.x * 128;
  const int tid = threadIdx.x, l = tid & 63, w = tid >> 6;
  const int g = l >> 4, ln = l & 15;

  f32x4 acc[4][2];
  #pragma unroll
  for (int i = 0; i < 4; ++i)
    #pragma unroll
    for (int j = 0; j < 2; ++j) acc[i][j] = (f32x4){0.f, 0.f, 0.f, 0.f};

  GEMM_STAGE64(Xb, Wt, 0, 0);
  #pragma unroll 1
  for (int kt = 0; kt < 16; ++kt) {
    const int cur = kt & 1;
    if (kt + 1 < 16) {
      GEMM_STAGE64(Xb, Wt, kt + 1, cur ^ 1);
      asm volatile("s_waitcnt vmcnt(6)" ::: "memory");
    } else {
      asm volatile("s_waitcnt vmcnt(0)" ::: "memory");
    }
    __builtin_amdgcn_s_barrier();
    const unsigned short* As = &AsB[cur][0];
    const unsigned short* Bs = &BsB[cur][0];
    if (sw) {
      GEMM_KLOOP64(b[j], a[i])
    } else {
      GEMM_KLOOP64(a[i], b[j])
    }
    asm volatile("" ::: "memory");
    __builtin_amdgcn_s_barrier();
  }

  if (sw) {
    // regs walk n (=d): packed stores along d for Q/K [b][h][s][d]
    unsigned short* dst = (z == 0) ? Qo : Ko;
    const float osc = (z == 0) ? QSCALE : 1.0f;
    #pragma unroll
    for (int j = 0; j < 2; ++j) {
      const int n = n0 + w * 32 + j * 16 + 4 * g;
      floatx4 bv_ = *(const floatx4*)(bias + n);
      const int h = n >> 6, d = n & 63;
      #pragma unroll
      for (int i = 0; i < 4; ++i) {
        const int m = m0 + i * 16 + ln;      // global s-row
        const int bb = m >> 11, ss = m & 2047;
        ushortx4 o;
        #pragma unroll
        for (int e = 0; e < 4; ++e) o[e] = bf16u((acc[i][j][e] + bv_[e]) * osc);
        *(ushortx4*)(dst + ((bb * NH + h) * SEQ + ss) * HD + d) = o;
      }
    }
  } else {
    // regs walk m (=s): packed stores along s for Vt [b][h][d][s]
    #pragma unroll
    for (int j = 0; j < 2; ++j) {
      const int n = n0 + w * 32 + j * 16 + ln;
      const float bgain = bias[n];
      const int h = n >> 6, d = n & 63;
      #pragma unroll
      for (int i = 0; i < 4; ++i) {
        const int mf = m0 + i * 16 + 4 * g;
        const int bb = mf >> 11, ss = mf & 2047;
        ushortx4 o;
        #pragma unroll
        for (int e = 0; e < 4; ++e) o[e] = bf16u(acc[i][j][e] + bgain);
        *(ushortx4*)(Vo + ((bb * NH + h) * HD + d) * SEQ + ss) = o;
      }
    }
  }
}

// ---------------------------------------------------------------------------
// Causal flash attention (r9 known-good: 66.5 us).  Unchanged from r16.
// ---------------------------------------------------------------------------
__global__ __launch_bounds__(512) void attn_kernel(
    const unsigned short* __restrict__ Q, const unsigned short* __restrict__ K,
    const unsigned short* __restrict__ Vt, unsigned short* __restrict__ O) {
  __shared__ __align__(16) unsigned short Kt[2][128 * 64];
  __shared__ __align__(16) unsigned short Vl[2][64 * 128];
  const int id = blockIdx.x;
  const int bh = id & 31;
  const int grp = id >> 5;
  const int T = (grp < 8) ? (15 - grp) : (grp - 8);
  const int h = bh & 15, b = bh >> 4;
  const int tid = threadIdx.x, l = tid & 63, w = tid >> 6;   // w = 0..7
  const int g = l >> 4, ln = l & 15;
  const size_t baseQK = (size_t)bh * SEQ * HD;   // [s][d]
  const size_t baseV = (size_t)bh * HD * SEQ;    // [d][s]
  const int xr = ln & 7;                          // K read-side swizzle xor
  const int srcA = ((g & 1) << 5) + ln;           // P-shuffle source lanes
  const int srcB = srcA + 16;
  const bool hi = (g >> 1) != 0;

  // K staging: chunks 2w,2w+1 of 16 (1KB = 8 rows x 128B)
  const int kr0 = (2 * w) * 8 + (l >> 3), kr1 = (2 * w + 1) * 8 + (l >> 3);
  const int kc0 = (l & 7) ^ (kr0 & 7), kc1 = (l & 7) ^ (kr1 & 7);
  // V staging: chunks 2w,2w+1 of 16 (1KB = 4 rows x 256B)
  const int vr0 = (2 * w) * 4 + (l >> 4), vr1 = (2 * w + 1) * 4 + (l >> 4);
  const int vc0 = (l & 15) ^ (vr0 & 15), vc1 = (l & 15) ^ (vr1 & 15);

  const int nkt = T + 1;
  const int qw = T * 128 + w * 16;

  // stage kt=0 into buf 0 (4 gload_lds per wave)
  gload16(K + baseQK + (size_t)kr0 * HD + kc0 * 8,
          (char*)&Kt[0][0] + (2 * w) * 1024);
  gload16(K + baseQK + (size_t)kr1 * HD + kc1 * 8,
          (char*)&Kt[0][0] + (2 * w + 1) * 1024);
  gload16(Vt + baseV + (size_t)vr0 * SEQ + vc0 * 8,
          (char*)&Vl[0][0] + (2 * w) * 1024);
  gload16(Vt + baseV + (size_t)vr1 * SEQ + vc1 * 8,
          (char*)&Vl[0][0] + (2 * w + 1) * 1024);

  // Q fragments (B-operand: col = q = ln, contraction d)
  const int qrow = qw + ln;
  short8 qf0 = *(const short8*)(Q + baseQK + (size_t)qrow * HD + g * 8);
  short8 qf1 = *(const short8*)(Q + baseQK + (size_t)qrow * HD + 32 + g * 8);

  float m_run = -1e30f, l_run = 0.f;
  f32x4 acc[4];
  #pragma unroll
  for (int dj = 0; dj < 4; ++dj) acc[dj] = (f32x4){0.f, 0.f, 0.f, 0.f};

  #pragma unroll 1
  for (int kt = 0; kt < nkt; ++kt) {
    const int cur = kt & 1;
    const bool has_next = (kt + 1 < nkt);
    if (has_next) {  // prefetch next 128-key tile into other buffer
      const int nxt = cur ^ 1;
      const size_t kof = (size_t)(kt + 1) * 128;
      gload16(K + baseQK + (kof + kr0) * HD + kc0 * 8,
              (char*)&Kt[nxt][0] + (2 * w) * 1024);
      gload16(K + baseQK + (kof + kr1) * HD + kc1 * 8,
              (char*)&Kt[nxt][0] + (2 * w + 1) * 1024);
      gload16(Vt + baseV + (size_t)vr0 * SEQ + kof + vc0 * 8,
              (char*)&Vl[nxt][0] + (2 * w) * 1024);
      gload16(Vt + baseV + (size_t)vr1 * SEQ + kof + vc1 * 8,
              (char*)&Vl[nxt][0] + (2 * w + 1) * 1024);
      asm volatile("s_waitcnt vmcnt(4)" ::: "memory");
    } else {
      asm volatile("s_waitcnt vmcnt(0)" ::: "memory");
    }
    __builtin_amdgcn_s_barrier();

    const bool last = (kt == T);
    const int jmax = last ? w : 7;

    // QK^T swapped: sv[j][e] = S[q=qw+ln][k = kt*128 + j*16 + 4g+e]
    f32x4 sv[8];
    #pragma unroll
    for (int j = 0; j < 8; ++j)
      sv[j] = (f32x4){-1e30f, -1e30f, -1e30f, -1e30f};
    __builtin_amdgcn_s_setprio(1);
    #pragma unroll
    for (int j = 0; j < 8; ++j) {
      if (j <= jmax) {
        f32x4 t = (f32x4){0.f, 0.f, 0.f, 0.f};
        short8 kf0 = *(const short8*)(
            &Kt[cur][(j * 16 + ln) * 64 + ((g ^ xr) * 8)]);
        t = mfma16(kf0, qf0, t);
        short8 kf1 = *(const short8*)(
            &Kt[cur][(j * 16 + ln) * 64 + (((4 + g) ^ xr) * 8)]);
        t = mfma16(kf1, qf1, t);
        if (last && j == w) {               // triangle tile
          #pragma unroll
          for (int e = 0; e < 4; ++e)
            sv[j][e] = (4 * g + e <= ln) ? t[e] : -1e30f;
        } else {
          sv[j] = t;
        }
      }
    }
    __builtin_amdgcn_s_setprio(0);

    // online softmax (exp2 domain), per q-row = per ln; max as tree
    float tj[8];
    #pragma unroll
    for (int j = 0; j < 8; ++j)
      tj[j] = fmaxf(fmaxf(sv[j][0], sv[j][1]), fmaxf(sv[j][2], sv[j][3]));
    float tm = fmaxf(fmaxf(fmaxf(tj[0], tj[1]), fmaxf(tj[2], tj[3])),
                     fmaxf(fmaxf(tj[4], tj[5]), fmaxf(tj[6], tj[7])));
    tm = fmaxf(tm, __shfl_xor(tm, 16));
    tm = fmaxf(tm, __shfl_xor(tm, 32));
    const float nm = fmaxf(m_run, tm);
    const float al = exp2f(m_run - nm);
    m_run = nm;

    // P = exp2(S - nm), packed to bf16 pairs per j
    unsigned pk[8][2];
    float rs = 0.f;
    #pragma unroll
    for (int j = 0; j < 8; ++j) {
      const float p0 = exp2f(sv[j][0] - nm), p1 = exp2f(sv[j][1] - nm);
      const float p2 = exp2f(sv[j][2] - nm), p3 = exp2f(sv[j][3] - nm);
      rs += (p0 + p1) + (p2 + p3);
      pk[j][0] = pkbf(p0, p1);
      pk[j][1] = pkbf(p2, p3);
    }
    rs += __shfl_xor(rs, 16);
    rs += __shfl_xor(rs, 32);
    l_run = l_run * al + rs;
    #pragma unroll
    for (int dj = 0; dj < 4; ++dj) acc[dj] *= al;

    // build PV B-fragments per 32-key slice ks:
    // lane (g,ln) needs P[q=ln][k = ks*32 + 8g..8g+7]
    const int ksmax = (jmax >> 1) + 1;
    short8 pf[4];
    #pragma unroll
    for (int ks = 0; ks < 4; ++ks) {
      if (ks < ksmax) {
        unsigned a0 = __shfl(pk[2 * ks][0], srcA);
        unsigned a1 = __shfl(pk[2 * ks][1], srcA);
        unsigned a2 = __shfl(pk[2 * ks][0], srcB);
        unsigned a3 = __shfl(pk[2 * ks][1], srcB);
        unsigned b0 = __shfl(pk[2 * ks + 1][0], srcA);
        unsigned b1 = __shfl(pk[2 * ks + 1][1], srcA);
        unsigned b2 = __shfl(pk[2 * ks + 1][0], srcB);
        unsigned b3 = __shfl(pk[2 * ks + 1][1], srcB);
        uintx4 u;
        u[0] = hi ? b0 : a0; u[1] = hi ? b1 : a1;
        u[2] = hi ? b2 : a2; u[3] = hi ? b3 : a3;
        pf[ks] = __builtin_bit_cast(short8, u);
      }
    }

    // PV swapped: acc rows = d (4g+e), cols = q (ln).
    // V LDS row = d (64 rows x 128 cols), colgroup swizzle ^= row&15 (=ln)
    __builtin_amdgcn_s_setprio(1);
    #pragma unroll
    for (int dj = 0; dj < 4; ++dj) {
      #pragma unroll
      for (int ks = 0; ks < 4; ++ks) {
        if (ks < ksmax) {
          short8 vb = *(const short8*)(
              &Vl[cur][(dj * 16 + ln) * 128 + (((ks * 4 + g) ^ ln) * 8)]);
          acc[dj] = mfma16(vb, pf[ks], acc[dj]);
        }
      }
    }
    __builtin_amdgcn_s_setprio(0);

    asm volatile("" ::: "memory");
    __builtin_amdgcn_s_barrier();
  }

  // epilogue: O[q = qw+ln][d = dj*16 + 4g+e], thread-local 1/l
  const float inv = 1.f / l_run;
  const size_t orow = ((size_t)b * SEQ + qw + ln) * EMB + h * HD;
  #pragma unroll
  for (int dj = 0; dj < 4; ++dj) {
    ushortx4 o;
    #pragma unroll
    for (int e = 0; e < 4; ++e) o[e] = bf16u(acc[dj][e] * inv);
    *(ushortx4*)(O + orow + dj * 16 + 4 * g) = o;
  }
}

// ---------------------------------------------------------------------------
// Output projection: fp32 out = AttnOut(bf16) @ Wo + bo.  (unchanged r16)
// 64x128 tile, wave index on N, 2-phase, vmcnt(6).  Grid (8,64).
// ---------------------------------------------------------------------------
__global__ __launch_bounds__(256) void gemm_o_kernel(
    const unsigned short* __restrict__ Ab, const unsigned short* __restrict__ Wt,
    const float* __restrict__ bias, float* __restrict__ out) {
  __shared__ __align__(16) unsigned short AsB[2][64 * 64];
  __shared__ __align__(16) unsigned short BsB[2][128 * 64];
  const int m0 = blockIdx.y * 64, n0 = blockIdx.x * 128;
  const int tid = threadIdx.x, l = tid & 63, w = tid >> 6;
  const int g = l >> 4, ln = l & 15;

  f32x4 acc[4][2];
  #pragma unroll
  for (int i = 0; i < 4; ++i)
    #pragma unroll
    for (int j = 0; j < 2; ++j) acc[i][j] = (f32x4){0.f, 0.f, 0.f, 0.f};

  GEMM_STAGE64(Ab, Wt, 0, 0);
  #pragma unroll 1
  for (int kt = 0; kt < 16; ++kt) {
    const int cur = kt & 1;
    if (kt + 1 < 16) {
      GEMM_STAGE64(Ab, Wt, kt + 1, cur ^ 1);
      asm volatile("s_waitcnt vmcnt(6)" ::: "memory");
    } else {
      asm volatile("s_waitcnt vmcnt(0)" ::: "memory");
    }
    __builtin_amdgcn_s_barrier();
    const unsigned short* As = &AsB[cur][0];
    const unsigned short* Bs = &BsB[cur][0];
    GEMM_KLOOP64(b[j], a[i])
    asm volatile("" ::: "memory");
    __builtin_amdgcn_s_barrier();
  }

  // epilogue: regs walk n; n = n0 + w*32 + j*16 + 4g, m = m0 + i*16 + ln
  #pragma unroll
  for (int j = 0; j < 2; ++j) {
    const int n = n0 + w * 32 + j * 16 + 4 * g;
    floatx4 bv_ = *(const floatx4*)(bias + n);
    #pragma unroll
    for (int i = 0; i < 4; ++i) {
      const int m = m0 + i * 16 + ln;
      floatx4 o = acc[i][j] + bv_;
      *(floatx4*)(out + (size_t)m * EMB + n) = o;
    }
  }
}

// ---------------------------------------------------------------------------
extern "C" void kernel_launch(void* const* d_in, const int* in_sizes, int n_in,
                              void* d_out, int out_size, void* d_ws, size_t ws_size,
                              hipStream_t stream) {
  const float* x  = (const float*)d_in[0];
  const float* Wq = (const float*)d_in[1];
  const float* bq = (const float*)d_in[2];
  const float* Wk = (const float*)d_in[3];
  const float* bk = (const float*)d_in[4];
  const float* Wv = (const float*)d_in[5];
  const float* bv = (const float*)d_in[6];
  const float* Wo = (const float*)d_in[7];
  const float* bo = (const float*)d_in[8];
  float* out = (float*)d_out;

  char* ws = (char*)d_ws;
  unsigned short* Xb  = (unsigned short*)(ws);              // 8 MB  [4096][1024]
  unsigned short* WqT = (unsigned short*)(ws + 8388608);    // 2 MB each [n][k]
  unsigned short* WkT = (unsigned short*)(ws + 10485760);
  unsigned short* WvT = (unsigned short*)(ws + 12582912);
  unsigned short* WoT = (unsigned short*)(ws + 14680064);
  unsigned short* Qb  = (unsigned short*)(ws + 16777216);   // 8 MB [b][h][s][d]
  unsigned short* Kb  = (unsigned short*)(ws + 25165824);   // 8 MB [b][h][s][d]
  unsigned short* Vtb = (unsigned short*)(ws + 33554432);   // 8 MB [b][h][d][s]
  unsigned short* Ao  = Xb;  // attention output reuses Xb (stream-ordered)

  hipLaunchKernelGGL(cvt_all_kernel, dim3(32, 32, 5), dim3(256), 0, stream,
                     x, Xb, Wq, Wk, Wv, Wo, WqT, WkT, WvT, WoT);
  hipLaunchKernelGGL(gemm_qkv_kernel, dim3(8, 64, 3), dim3(256), 0, stream,
                     Xb, WqT, WkT, WvT, bq, bk, bv, Qb, Kb, Vtb);
  hipLaunchKernelGGL(attn_kernel, dim3(512), dim3(512), 0, stream,
                     Qb, Kb, Vtb, Ao);
  hipLaunchKernelGGL(gemm_o_kernel, dim3(8, 64), dim3(256), 0, stream,
                     Ao, WoT, bo, out);
}